// Round 14
// baseline (117.396 us; speedup 1.0000x reference)
//
#include <hip/hip_runtime.h>
#include <cstdint>
#include <cstddef>

#define B_  16
#define C_  128
#define N_  2048
#define K_  4
#define O_  64
#define C2_ 256   // 2*C
#define ED_ 320   // 2*C + O
#define NM_ 4096  // N*R
#define AGC 384   // channels per ag row

typedef float  f32x4  __attribute__((ext_vector_type(4)));
typedef short  s16x8  __attribute__((ext_vector_type(8)));
typedef __bf16 bf16x4 __attribute__((ext_vector_type(4)));
typedef __bf16 bf16x8 __attribute__((ext_vector_type(8)));
typedef unsigned short u16;
typedef unsigned int   u32;
typedef unsigned int   u32x4 __attribute__((ext_vector_type(4)));

__device__ __forceinline__ u32 umin32(u32 a, u32 b) { return a < b ? a : b; }
__device__ __forceinline__ u32 umax32(u32 a, u32 b) { return a > b ? a : b; }
__device__ __forceinline__ float bf2f(u16 h) { return __builtin_bit_cast(float, (u32)h << 16); }

// median of 3 u32 — single VOP3; branchless depth-1 sorted insert
__device__ __forceinline__ u32 med3u(u32 v, u32 a, u32 b) {
  u32 r;
  asm("v_med3_u32 %0, %1, %2, %3" : "=v"(r) : "v"(v), "v"(a), "v"(b));
  return r;
}

__device__ __forceinline__ s16x8 ldw_bf16(const float* __restrict__ p) {
  float4 a = *(const float4*)p;
  float4 c = *(const float4*)(p + 4);
  bf16x8 r;
  r[0] = (__bf16)a.x; r[1] = (__bf16)a.y; r[2] = (__bf16)a.z; r[3] = (__bf16)a.w;
  r[4] = (__bf16)c.x; r[5] = (__bf16)c.y; r[6] = (__bf16)c.z; r[7] = (__bf16)c.w;
  return __builtin_bit_cast(s16x8, r);
}

__device__ __forceinline__ u32 relu2(u32 u) {
  u32 s = u & 0x80008000u;
  u32 m = s - (s >> 15);
  return u & ~(m | s);
}
__device__ __forceinline__ s16x8 relu8(s16x8 v) {
  u32x4 u = __builtin_bit_cast(u32x4, v);
  u[0] = relu2(u[0]); u[1] = relu2(u[1]);
  u[2] = relu2(u[2]); u[3] = relu2(u[3]);
  return __builtin_bit_cast(s16x8, u);
}

__device__ __forceinline__ void glds16(const void* g, void* l) {
  __builtin_amdgcn_global_load_lds(
      (const __attribute__((address_space(1))) u32*)g,
      (__attribute__((address_space(3))) u32*)l, 16, 0, 0);
}

// ============ prep: xx, xT32, xh (bf16 rows, chunk XOR-swizzled), wh, wg ============
__global__ __launch_bounds__(256) void prep_kernel(const float* __restrict__ x,
                                                   const float* __restrict__ w1,
                                                   const float* __restrict__ w2,
                                                   const float* __restrict__ w3,
                                                   float* __restrict__ xT32,
                                                   u16* __restrict__ xh,
                                                   float* __restrict__ xx,
                                                   u16* __restrict__ wh,
                                                   u16* __restrict__ wg) {
  const int t = threadIdx.x;
  if (blockIdx.y == B_) {
    const int gid = blockIdx.x * 256 + t;   // 0..8191
    for (int i = gid; i < 15360; i += 8192) {
      const float* src; u16* dst;
      if (i < 4096)       { src = w1 + (size_t)i * 4;            dst = wh + (size_t)i * 4; }
      else if (i < 14336) { src = w2 + (size_t)(i - 4096) * 4;   dst = wh + 16384 + (size_t)(i - 4096) * 4; }
      else                { src = w3 + (size_t)(i - 14336) * 4;  dst = wh + 57344 + (size_t)(i - 14336) * 4; }
      float4 v = *(const float4*)src;
      ushort4 h;
      h.x = __builtin_bit_cast(u16, (__bf16)v.x);
      h.y = __builtin_bit_cast(u16, (__bf16)v.y);
      h.z = __builtin_bit_cast(u16, (__bf16)v.z);
      h.w = __builtin_bit_cast(u16, (__bf16)v.w);
      *(ushort4*)dst = h;
    }
    if (wg) {
      for (int i = gid; i < 12288; i += 8192) {
        int r = i >> 5;
        int c4 = (i & 31) * 4;
        const float* src;
        if (r < 64)       src = w1 + (size_t)r * C2_ + c4;
        else if (r < 128) src = w1 + (size_t)(r - 64) * C2_ + 128 + c4;
        else if (r < 256) src = w2 + (size_t)(r - 128) * ED_ + 64 + c4;
        else              src = w2 + (size_t)(r - 256) * ED_ + 192 + c4;
        float4 v = *(const float4*)src;
        ushort4 h;
        h.x = __builtin_bit_cast(u16, (__bf16)v.x);
        h.y = __builtin_bit_cast(u16, (__bf16)v.y);
        h.z = __builtin_bit_cast(u16, (__bf16)v.z);
        h.w = __builtin_bit_cast(u16, (__bf16)v.w);
        *(ushort4*)&wg[(size_t)r * 128 + c4] = h;
      }
    }
    return;
  }

  __shared__ __align__(16) float sx[C_][65];
  const int b = blockIdx.y, n0 = blockIdx.x * 64;
  const float* xb = x + (size_t)b * C_ * N_;
  for (int u = t; u < C_ * 16; u += 256) {
    int c = u >> 4, f4 = u & 15;
    float4 v = *(const float4*)&xb[(size_t)c * N_ + n0 + f4 * 4];
    sx[c][f4 * 4 + 0] = v.x; sx[c][f4 * 4 + 1] = v.y;
    sx[c][f4 * 4 + 2] = v.z; sx[c][f4 * 4 + 3] = v.w;
  }
  __syncthreads();
  if (t < 64) {
    float s = 0.f;
    for (int c = 0; c < C_; ++c) { float v = sx[c][t]; s = fmaf(v, v, s); }
    xx[b * N_ + n0 + t] = s;
  }
  for (int u = t; u < 64 * 16; u += 256) {
    int n = u >> 4, cb = u & 15;
    float vv[8]; s16x8 hv;
#pragma unroll
    for (int j = 0; j < 8; ++j) {
      float v = sx[cb * 8 + j][n];
      vv[j] = v;
      hv[j] = (short)__builtin_bit_cast(u16, (__bf16)v);
    }
    size_t ro = ((size_t)b * N_ + n0 + n) * C_;
    *(float4*)&xT32[ro + cb * 8]     = make_float4(vv[0], vv[1], vv[2], vv[3]);
    *(float4*)&xT32[ro + cb * 8 + 4] = make_float4(vv[4], vv[5], vv[6], vv[7]);
    int sc = cb ^ (n & 7);
    *(s16x8*)&xh[ro + sc * 8] = hv;
  }
}

// ============ knn: 512 thr, 128 queries/block, 8 chains/lane, barrier-free main loop ============
// Each wave owns 16 m-rows per 128-row step (16 steps). Fragments+xx global->reg,
// prefetched one step ahead. LDS only for merge + fused exact-fp32 rerank.
// key = bits(dd + 512) (dd >= -xx[q] -> positive -> bit-monotone), low 11 bits = idx.
__global__ __launch_bounds__(512) void knn_mfma(const u16* __restrict__ xh,
                                                const float* __restrict__ xT32,
                                                const float* __restrict__ xx,
                                                int* __restrict__ knn_out) {
  __shared__ __align__(16) u32 cd[128 * 161 + 1024 + 1024];  // merge | ci[128][8] | sdv[128][8]
  u32*   cim = cd + 128 * 161;
  float* sdv = (float*)(cd + 128 * 161 + 1024);
  const int b = blockIdx.y, q0 = blockIdx.x * 128;
  const int t = threadIdx.x;
  const int wv = t >> 6, lq = t & 15, lh = (t >> 4) & 3;
  const u16* xhb = xh + (size_t)b * N_ * C_;
  const float* xxb = xx + b * N_;

  // Q fragments (B-operand): 8 query tiles x 4 k-slices, registers for the main loop
  s16x8 qf[8][4];
#pragma unroll
  for (int qt = 0; qt < 8; ++qt)
#pragma unroll
    for (int ks = 0; ks < 4; ++ks) {
      int q = q0 + qt * 16 + lq;
      int ch = (ks * 4 + lh) ^ (q & 7);
      qf[qt][ks] = *(const s16x8*)&xhb[(size_t)q * C_ + ch * 8];
    }

  u32 pk[8][5];   // sorted ascending per chain
#pragma unroll
  for (int qt = 0; qt < 8; ++qt)
#pragma unroll
    for (int s = 0; s < 5; ++s) pk[qt][s] = 0xFFFFFFFFu;

  const int rbase = wv * 16 + lq;   // this wave's m-row for A-fragments
  int choff[4];
#pragma unroll
  for (int ks = 0; ks < 4; ++ks) choff[ks] = ((ks * 4 + lh) ^ (lq & 7)) * 8;

  auto loadf = [&](int step, s16x8* d) {
    const u16* rp = xhb + (size_t)(step * 128 + rbase) * C_;
#pragma unroll
    for (int ks = 0; ks < 4; ++ks) d[ks] = *(const s16x8*)&rp[choff[ks]];
  };
  auto loadxx = [&](int step) -> f32x4 {
    return *(const f32x4*)&xxb[step * 128 + wv * 16 + lh * 4];
  };
  auto dostep = [&](int step, const s16x8* mf, f32x4 xm4) {
    f32x4 acc[8];
#pragma unroll
    for (int qt = 0; qt < 8; ++qt) acc[qt] = (f32x4){0.f, 0.f, 0.f, 0.f};
#pragma unroll
    for (int ks = 0; ks < 4; ++ks)
#pragma unroll
      for (int qt = 0; qt < 8; ++qt)
        acc[qt] = __builtin_amdgcn_mfma_f32_16x16x32_bf16(mf[ks], qf[qt][ks], acc[qt], 0, 0, 0);
    const int mrow = step * 128 + wv * 16 + lh * 4;
    float xma[4] = {xm4[0] + 512.f, xm4[1] + 512.f, xm4[2] + 512.f, xm4[3] + 512.f};
#pragma unroll
    for (int r = 0; r < 4; ++r) {
#pragma unroll
      for (int qt = 0; qt < 8; ++qt) {   // 8 independent chains, depth-1 insert
        float dd = fmaf(acc[qt][r], -2.f, xma[r]);   // dd+512 > 0 always
        u32 u = __builtin_bit_cast(u32, dd);
        u32 v = (u & 0xFFFFF800u) | (u32)(mrow + r);
        u32 n0 = umin32(v, pk[qt][0]);
        u32 n1 = med3u(v, pk[qt][0], pk[qt][1]);
        u32 n2 = med3u(v, pk[qt][1], pk[qt][2]);
        u32 n3 = med3u(v, pk[qt][2], pk[qt][3]);
        u32 n4 = med3u(v, pk[qt][3], pk[qt][4]);
        pk[qt][0] = n0; pk[qt][1] = n1; pk[qt][2] = n2;
        pk[qt][3] = n3; pk[qt][4] = n4;
      }
    }
  };

  // double-buffered in named regs (fragments AND xx prefetched one step ahead)
  s16x8 fa[4], fb[4];
  f32x4 xa, xb4;
  loadf(0, fa);
  loadf(1, fb);
  xa = loadxx(0);
  xb4 = loadxx(1);
  for (int step = 0; step < 16; step += 2) {
    dostep(step, fa, xa);
    if (step + 2 < 16) { loadf(step + 2, fa); xa = loadxx(step + 2); }
    dostep(step + 1, fb, xb4);
    if (step + 3 < 16) { loadf(step + 3, fb); xb4 = loadxx(step + 3); }
  }

  // merge: per local q, 32 units x 5 packed candidates (stride 161 - odd, no camping)
  const int unit = wv * 4 + lh;   // 0..31
#pragma unroll
  for (int qt = 0; qt < 8; ++qt) {
    int ql = qt * 16 + lq;
#pragma unroll
    for (int s = 0; s < 5; ++s) cd[ql * 161 + unit * 5 + s] = pk[qt][s];
  }
  __syncthreads();
  if (t < 128) {
    u32 fd[8];
#pragma unroll
    for (int s = 0; s < 8; ++s) fd[s] = 0xFFFFFFFFu;
    for (int j = 0; j < 160; ++j) {
      u32 v = cd[t * 161 + j];
      u32 m0 = umin32(v, fd[0]);
      u32 m1 = med3u(v, fd[0], fd[1]);
      u32 m2 = med3u(v, fd[1], fd[2]);
      u32 m3 = med3u(v, fd[2], fd[3]);
      u32 m4 = med3u(v, fd[3], fd[4]);
      u32 m5 = med3u(v, fd[4], fd[5]);
      u32 m6 = med3u(v, fd[5], fd[6]);
      u32 m7 = med3u(v, fd[6], fd[7]);
      fd[0] = m0; fd[1] = m1; fd[2] = m2; fd[3] = m3;
      fd[4] = m4; fd[5] = m5; fd[6] = m6; fd[7] = m7;
    }
#pragma unroll
    for (int s = 0; s < 8; ++s) cim[t * 8 + s] = fd[s] & 0x7FFu;
  }
  __syncthreads();

  // ---- fused exact fp32 rerank of the 8 candidates (512 threads, 2 dots each) ----
  {
    const float* xb32 = xT32 + (size_t)b * N_ * C_;
    const int ql = t >> 2, cs = t & 3;   // ql 0..127
    const float* qr = xb32 + (size_t)(q0 + ql) * C_;
#pragma unroll
    for (int cc = 0; cc < 2; ++cc) {
      int cslot = cs + cc * 4;
      int idx = (int)cim[ql * 8 + cslot];
      const float* mr = xb32 + (size_t)idx * C_;
      float a0 = 0.f, a1 = 0.f, a2 = 0.f, a3 = 0.f;
#pragma unroll 8
      for (int i = 0; i < 32; ++i) {
        float4 qv = *(const float4*)&qr[i * 4];
        float4 mv = *(const float4*)&mr[i * 4];
        a0 = fmaf(qv.x, mv.x, a0); a1 = fmaf(qv.y, mv.y, a1);
        a2 = fmaf(qv.z, mv.z, a2); a3 = fmaf(qv.w, mv.w, a3);
      }
      float dot = (a0 + a1) + (a2 + a3);
      sdv[ql * 8 + cslot] = xxb[idx] - 2.f * dot;
    }
  }
  __syncthreads();
  if (t < 128) {
    float dloc[8]; int iloc[8];
#pragma unroll
    for (int j = 0; j < 8; ++j) { dloc[j] = sdv[t * 8 + j]; iloc[j] = (int)cim[t * 8 + j]; }
    u32 used = 0;
#pragma unroll
    for (int s = 0; s < 4; ++s) {
      float bdv = 1e30f; int bidx = 0x7fffffff; int bj = 0;
#pragma unroll
      for (int j = 0; j < 8; ++j) {
        if (!((used >> j) & 1)) {
          bool bet = (dloc[j] < bdv) || (dloc[j] == bdv && iloc[j] < bidx);
          if (bet) { bdv = dloc[j]; bidx = iloc[j]; bj = j; }
        }
      }
      used |= 1u << bj;
      knn_out[((size_t)b * N_ + q0 + t) * K_ + s] = bidx;
    }
  }
}

// ============ agemm: ag[m][384] = wg @ [x; relu(x)] slices, biases folded ============
__global__ __launch_bounds__(256, 2) void agemm_kernel(
    const u16* __restrict__ xh, const u16* __restrict__ wg,
    const float* __restrict__ b1, const float* __restrict__ b2,
    u16* __restrict__ ag) {
  __shared__ __align__(16) char sm[66560];
  u16* outT = (u16*)(sm + 16384);
  const int b = blockIdx.y, m0 = blockIdx.x * 64;
  const int t = threadIdx.x, lane = t & 63, wv = t >> 6, lq = t & 15, lh = (t >> 4) & 3;
  const u16* xhb = xh + (size_t)b * N_ * C_;

  {
    const char* s = (const char*)(xhb + (size_t)m0 * C_);
#pragma unroll
    for (int c = 0; c < 4; ++c) {
      int off = (wv * 4 + c) * 1024;
      glds16(s + off + lane * 16, sm + off);
    }
  }

  s16x8 af[6][4];
#pragma unroll
  for (int rt = 0; rt < 6; ++rt)
#pragma unroll
    for (int ks = 0; ks < 4; ++ks)
      af[rt][ks] = *(const s16x8*)&wg[(size_t)(wv * 96 + rt * 16 + lq) * 128 + ks * 32 + lh * 8];

  f32x4 acc[6][4];
#pragma unroll
  for (int rt = 0; rt < 6; ++rt)
#pragma unroll
    for (int cg = 0; cg < 4; ++cg) acc[rt][cg] = (f32x4){0.f, 0.f, 0.f, 0.f};

  asm volatile("s_waitcnt vmcnt(0)");
  __syncthreads();

#pragma unroll
  for (int cg = 0; cg < 4; ++cg) {
    s16x8 braw[4], brel[4];
#pragma unroll
    for (int ks = 0; ks < 4; ++ks) {
      int row = cg * 16 + lq;
      braw[ks] = *(const s16x8*)(sm + row * 256 + (((ks * 4 + lh) ^ (lq & 7)) * 16));
      brel[ks] = relu8(braw[ks]);
    }
#pragma unroll
    for (int rt = 0; rt < 6; ++rt) {
      const bool rl = (wv * 96 + rt * 16) >= 128;
#pragma unroll
      for (int ks = 0; ks < 4; ++ks)
        acc[rt][cg] = __builtin_amdgcn_mfma_f32_16x16x32_bf16(
            af[rt][ks], rl ? brel[ks] : braw[ks], acc[rt][cg], 0, 0, 0);
    }
  }

#pragma unroll
  for (int rt = 0; rt < 6; ++rt) {
    const int ch0 = wv * 96 + rt * 16 + lh * 4;
    float bias[4];
#pragma unroll
    for (int r = 0; r < 4; ++r) {
      int c = ch0 + r;
      bias[r] = (c < 64) ? b1[c] : ((c >= 128 && c < 256) ? b2[c - 128] : 0.f);
    }
#pragma unroll
    for (int cg = 0; cg < 4; ++cg) {
      bf16x4 st;
#pragma unroll
      for (int r = 0; r < 4; ++r) st[r] = (__bf16)(acc[rt][cg][r] + bias[r]);
      *(bf16x4*)&outT[(size_t)(cg * 16 + lq) * 392 + ch0] = st;
    }
  }
  __syncthreads();

  {
    const int row = t >> 2, p = t & 3;
#pragma unroll
    for (int k = 0; k < 12; ++k) {
      int seg = k * 4 + p;
      *(u32x4*)&ag[((size_t)b * N_ + m0 + row) * AGC + seg * 8] =
          *(const u32x4*)&outT[(size_t)row * 392 + seg * 8];
    }
  }
}

// ============ fused_ag: gathers of precomputed ag + small GEMMs ============
__global__ __launch_bounds__(256, 3) void fused_ag(
    const u16* __restrict__ ag, const u16* __restrict__ wh,
    const int* __restrict__ knn_idx,
    const float* __restrict__ b3, float* __restrict__ out) {
  __shared__ __align__(16) char fsm[44032];
  u16* e1T = (u16*)fsm;
  u16* s2T = (u16*)(fsm + 9216);
  u16* e2T = (u16*)(fsm + 26624);
  float* oSt = (float*)fsm;   // [64][36], aliases e1T after p2 frag reads

  const int t = threadIdx.x, wv = t >> 6, lq = t & 15, lh = (t >> 4) & 3;
  const int b = blockIdx.y, n0 = blockIdx.x * 16;
  const u16* agb = ag + (size_t)b * N_ * AGC;
  const u16* w2h = wh + 16384;   // [128][320]
  const u16* w3h = wh + 57344;   // [64][64]

  s16x8 w2f[2][2];
#pragma unroll
  for (int rt = 0; rt < 2; ++rt)
#pragma unroll
    for (int ks = 0; ks < 2; ++ks)
      w2f[rt][ks] = *(const s16x8*)&w2h[(size_t)(wv * 32 + rt * 16 + lq) * ED_ + ks * 32 + lh * 8];
  const s16x8 w3a = *(const s16x8*)&w3h[(size_t)(wv * 16 + lq) * O_ + lh * 8];
  const s16x8 w3b = *(const s16x8*)&w3h[(size_t)(wv * 16 + lq) * O_ + 32 + lh * 8];
  const float4 b3v = *(const float4*)&b3[wv * 16 + lh * 4];

  {
    const int col = t >> 2, p = t & 3;
    const int n = n0 + (col >> 2);
    const int nid = knn_idx[((size_t)b * N_ + n) * K_ + (col & 3)];
    const u16* rc = agb + (size_t)n * AGC;
    const u16* rn = agb + (size_t)nid * AGC;
#pragma unroll
    for (int q = 0; q < 2; ++q) {
      s16x8 va = *(const s16x8*)&rc[p * 16 + q * 8];
      s16x8 vb = *(const s16x8*)&rn[64 + p * 16 + q * 8];
      bf16x8 r;
#pragma unroll
      for (int j = 0; j < 8; ++j)
        r[j] = (__bf16)fmaxf(bf2f((u16)va[j]) + bf2f((u16)vb[j]), 0.f);
      *(bf16x8*)&e1T[(size_t)col * 72 + p * 16 + q * 8] = r;
    }
#pragma unroll
    for (int q = 0; q < 4; ++q) {
      s16x8 va = *(const s16x8*)&rc[128 + p * 32 + q * 8];
      s16x8 vb = *(const s16x8*)&rn[256 + p * 32 + q * 8];
      bf16x8 r;
#pragma unroll
      for (int j = 0; j < 8; ++j)
        r[j] = (__bf16)(bf2f((u16)va[j]) + bf2f((u16)vb[j]));
      *(bf16x8*)&s2T[(size_t)col * 136 + p * 32 + q * 8] = r;
    }
  }
  __syncthreads();   // B1

  {
    f32x4 acc[2][4];
#pragma unroll
    for (int rt = 0; rt < 2; ++rt)
#pragma unroll
      for (int cg = 0; cg < 4; ++cg) acc[rt][cg] = (f32x4){0.f, 0.f, 0.f, 0.f};
#pragma unroll
    for (int ks = 0; ks < 2; ++ks)
#pragma unroll
      for (int cg = 0; cg < 4; ++cg) {
        s16x8 bf = *(const s16x8*)&e1T[(size_t)(cg * 16 + lq) * 72 + ks * 32 + lh * 8];
#pragma unroll
        for (int rt = 0; rt < 2; ++rt)
          acc[rt][cg] = __builtin_amdgcn_mfma_f32_16x16x32_bf16(w2f[rt][ks], bf, acc[rt][cg], 0, 0, 0);
      }
#pragma unroll
    for (int rt = 0; rt < 2; ++rt)
#pragma unroll
      for (int cg = 0; cg < 4; ++cg) {
        const int col = cg * 16 + lq;
        const int j0 = wv * 32 + rt * 16 + lh * 4;
        ushort4 sv = *(const ushort4*)&s2T[(size_t)col * 136 + j0];
        bf16x4 st;
        st[0] = (__bf16)fmaxf(acc[rt][cg][0] + bf2f(sv.x), 0.f);
        st[1] = (__bf16)fmaxf(acc[rt][cg][1] + bf2f(sv.y), 0.f);
        st[2] = (__bf16)fmaxf(acc[rt][cg][2] + bf2f(sv.z), 0.f);
        st[3] = (__bf16)fmaxf(acc[rt][cg][3] + bf2f(sv.w), 0.f);
        *(bf16x4*)&e2T[(size_t)col * 136 + j0] = st;
      }
  }
  __syncthreads();   // B2

  {
#pragma unroll
    for (int cg = 0; cg < 8; ++cg) {
      int col = cg * 16 + lq;
      int nl = col >> 3, rr = (col >> 2) & 1, kk = col & 3;
      int row = nl * 4 + kk;
      s16x8 f1 = *(const s16x8*)&e2T[(size_t)row * 136 + rr * 64 + lh * 8];
      s16x8 f2 = *(const s16x8*)&e2T[(size_t)row * 136 + rr * 64 + 32 + lh * 8];
      f32x4 acc = {0.f, 0.f, 0.f, 0.f};
      acc = __builtin_amdgcn_mfma_f32_16x16x32_bf16(w3a, f1, acc, 0, 0, 0);
      acc = __builtin_amdgcn_mfma_f32_16x16x32_bf16(w3b, f2, acc, 0, 0, 0);
      float vv[4];
#pragma unroll
      for (int r = 0; r < 4; ++r) {
        float v = acc[r];
        v = fmaxf(v, __shfl_xor(v, 1));
        v = fmaxf(v, __shfl_xor(v, 2));
        vv[r] = v;
      }
      if ((lq & 3) == 0) {
        int mloc = col >> 2;
        int o = wv * 16 + lh * 4;
        const float b3a[4] = {b3v.x, b3v.y, b3v.z, b3v.w};
#pragma unroll
        for (int r = 0; r < 4; ++r) oSt[(size_t)(o + r) * 36 + mloc] = vv[r] + b3a[r];
      }
    }
  }
  __syncthreads();   // B3

#pragma unroll
  for (int io = 0; io < 2; ++io) {
    int u = t + io * 256;
    int o = u >> 3, seg = u & 7;
    *(float4*)&out[((size_t)b * O_ + o) * NM_ + n0 * 2 + seg * 4] =
        *(const float4*)&oSt[(size_t)o * 36 + seg * 4];
  }
}

// ============ slow fallback kernels ============
__global__ __launch_bounds__(256) void xx_kernel(const float* __restrict__ x,
                                                 float* __restrict__ xx) {
  int g = blockIdx.x * 256 + threadIdx.x;
  int b = g >> 11;
  int n = g & (N_ - 1);
  const float* xp = x + (size_t)b * C_ * N_ + n;
  float s = 0.f;
#pragma unroll 8
  for (int c = 0; c < C_; ++c) { float v = xp[(size_t)c * N_]; s += v * v; }
  xx[g] = s;
}

__global__ __launch_bounds__(256) void knn_kernel(const float* __restrict__ x,
                                                  const float* __restrict__ xx,
                                                  int* __restrict__ knn_out) {
  __shared__ __align__(16) float qT[C_ * 64];
  __shared__ __align__(16) float mT[C_ * 64];
  const int b = blockIdx.y;
  const int q0 = blockIdx.x * 64;
  const int t = threadIdx.x;
  const float* xb = x + (size_t)b * C_ * N_;
  const float* xxb = xx + b * N_;
  for (int i = t; i < C_ * 64; i += 256) {
    int c = i >> 6, q = i & 63;
    qT[i] = xb[(size_t)c * N_ + q0 + q];
  }
  const int tq = t & 15;
  const int tm = t >> 4;
  float bd[4][4]; int bi[4][4];
#pragma unroll
  for (int a = 0; a < 4; ++a)
#pragma unroll
    for (int s = 0; s < 4; ++s) { bd[a][s] = 1e30f; bi[a][s] = 0; }
  for (int m0 = 0; m0 < N_; m0 += 64) {
    __syncthreads();
    for (int i = t; i < C_ * 64; i += 256) {
      int c = i >> 6, m = i & 63;
      mT[i] = xb[(size_t)c * N_ + m0 + m];
    }
    __syncthreads();
    float acc[4][4];
#pragma unroll
    for (int a = 0; a < 4; ++a)
#pragma unroll
      for (int j = 0; j < 4; ++j) acc[a][j] = 0.f;
#pragma unroll 4
    for (int c = 0; c < C_; ++c) {
      float4 qv = *(const float4*)&qT[c * 64 + tq * 4];
      float4 mv = *(const float4*)&mT[c * 64 + tm * 4];
      float qa[4] = {qv.x, qv.y, qv.z, qv.w};
      float ma[4] = {mv.x, mv.y, mv.z, mv.w};
#pragma unroll
      for (int a = 0; a < 4; ++a)
#pragma unroll
        for (int j = 0; j < 4; ++j) acc[a][j] += qa[a] * ma[j];
    }
#pragma unroll
    for (int j = 0; j < 4; ++j) {
      float xm = xxb[m0 + tm * 4 + j];
      int id = m0 + tm * 4 + j;
#pragma unroll
      for (int a = 0; a < 4; ++a) {
        float d = xm - 2.f * acc[a][j];
        if (d < bd[a][3]) {
          bd[a][3] = d; bi[a][3] = id;
#pragma unroll
          for (int s = 3; s > 0; --s)
            if (bd[a][s] < bd[a][s - 1]) {
              float td = bd[a][s]; bd[a][s] = bd[a][s - 1]; bd[a][s - 1] = td;
              int ti = bi[a][s]; bi[a][s] = bi[a][s - 1]; bi[a][s - 1] = ti;
            }
        }
      }
    }
  }
  __syncthreads();
  float* cd = qT;
  int* ci = (int*)mT;
#pragma unroll
  for (int a = 0; a < 4; ++a) {
    int q = tq * 4 + a;
#pragma unroll
    for (int s = 0; s < 4; ++s) {
      cd[q * 64 + tm * 4 + s] = bd[a][s];
      ci[q * 64 + tm * 4 + s] = bi[a][s];
    }
  }
  __syncthreads();
  if (t < 64) {
    float fd[4]; int fi[4];
#pragma unroll
    for (int s = 0; s < 4; ++s) { fd[s] = 1e30f; fi[s] = 0; }
    for (int j = 0; j < 64; ++j) {
      float d = cd[t * 64 + j];
      int id = ci[t * 64 + j];
      if (d < fd[3]) {
        fd[3] = d; fi[3] = id;
#pragma unroll
        for (int s = 3; s > 0; --s)
          if (fd[s] < fd[s - 1]) {
            float td = fd[s]; fd[s] = fd[s - 1]; fd[s - 1] = td;
            int ti = fi[s]; fi[s] = fi[s - 1]; fi[s - 1] = ti;
          }
      }
    }
#pragma unroll
    for (int s = 0; s < 4; ++s)
      knn_out[(b * N_ + q0 + t) * K_ + s] = fi[s];
  }
}

__global__ __launch_bounds__(256, 5) void fused_fb(
    const float* __restrict__ x, const int* __restrict__ knn_idx,
    const float* __restrict__ w1, const float* __restrict__ b1,
    const float* __restrict__ w2, const float* __restrict__ b2,
    const float* __restrict__ w3, const float* __restrict__ b3,
    float* __restrict__ out) {
  __shared__ __align__(16) char fsm[30976];
  __bf16 (*cT)[136]  = (__bf16(*)[136])(fsm);
  __bf16 (*e1T)[72]  = (__bf16(*)[72])(fsm + 4352);
  float  (*oSt)[36]  = (float(*)[36])(fsm + 4352);
  __bf16 (*nT)[136]  = (__bf16(*)[136])(fsm + 13568);
  __bf16 (*e2T)[136] = (__bf16(*)[136])(fsm + 13568);

  const int b  = blockIdx.y;
  const int n0 = blockIdx.x * 16;
  const int t  = threadIdx.x;
  const float* xb = x + (size_t)b * C_ * N_;

  {
    const int stn = t >> 4, stc = t & 15;
    const int kbase = (b * N_ + n0) * K_;
    const float* srcc = xb + (size_t)(stc * 8) * N_ + n0 + stn;
    bf16x8 raw;
#pragma unroll
    for (int j = 0; j < 8; ++j) raw[j] = (__bf16)srcc[(size_t)j * N_];
    *(bf16x8*)&cT[stn][stc * 8] = raw;
#pragma unroll
    for (int it = 0; it < 4; ++it) {
      int col = stn + 16 * it;
      int nid = knn_idx[kbase + col];
      const float* src = xb + (size_t)(stc * 8) * N_ + nid;
      bf16x8 rw;
#pragma unroll
      for (int j = 0; j < 8; ++j) rw[j] = (__bf16)src[(size_t)j * N_];
      *(bf16x8*)&nT[col][stc * 8] = rw;
    }
  }
  __syncthreads();

  const int lq = t & 15;
  const int lh = (t >> 4) & 3;
  const int wv = t >> 6;

  {
    const float* w1r = w1 + (size_t)(wv * 16 + lq) * C2_;
    f32x4 acc[4];
#pragma unroll
    for (int cg = 0; cg < 4; ++cg) acc[cg] = (f32x4){0.f, 0.f, 0.f, 0.f};
#pragma unroll
    for (int ks = 0; ks < 8; ++ks) {
      s16x8 a = ldw_bf16(w1r + ks * 32 + lh * 8);
#pragma unroll
      for (int cg = 0; cg < 4; ++cg) {
        const __bf16* bp = (ks < 4)
            ? &cT[cg * 4 + (lq >> 2)][ks * 32 + lh * 8]
            : &nT[cg * 16 + lq][(ks - 4) * 32 + lh * 8];
        acc[cg] = __builtin_amdgcn_mfma_f32_16x16x32_bf16(
            a, *(const s16x8*)bp, acc[cg], 0, 0, 0);
      }
    }
#pragma unroll
    for (int cg = 0; cg < 4; ++cg) {
      bf16x4 st;
#pragma unroll
      for (int r = 0; r < 4; ++r) {
        float v = acc[cg][r] + b1[wv * 16 + lh * 4 + r];
        st[r] = (__bf16)fmaxf(v, 0.f);
      }
      *(bf16x4*)&e1T[cg * 16 + lq][wv * 16 + lh * 4] = st;
    }
  }
  __syncthreads();

  f32x4 acc2[2][4];
  {
    const float* w2r0 = w2 + (size_t)(wv * 32 + lq) * ED_;
    const float* w2r1 = w2r0 + (size_t)16 * ED_;
#pragma unroll
    for (int ro = 0; ro < 2; ++ro)
#pragma unroll
      for (int cg = 0; cg < 4; ++cg) acc2[ro][cg] = (f32x4){0.f, 0.f, 0.f, 0.f};
#pragma unroll
    for (int ks = 0; ks < 10; ++ks) {
      s16x8 a0 = ldw_bf16(w2r0 + ks * 32 + lh * 8);
      s16x8 a1 = ldw_bf16(w2r1 + ks * 32 + lh * 8);
#pragma unroll
      for (int cg = 0; cg < 4; ++cg) {
        s16x8 bf;
        if (ks < 2)      bf = *(const s16x8*)&e1T[cg * 16 + lq][ks * 32 + lh * 8];
        else if (ks < 6) bf = relu8(*(const s16x8*)&cT[cg * 4 + (lq >> 2)][(ks - 2) * 32 + lh * 8]);
        else             bf = relu8(*(const s16x8*)&nT[cg * 16 + lq][(ks - 6) * 32 + lh * 8]);
        acc2[0][cg] = __builtin_amdgcn_mfma_f32_16x16x32_bf16(a0, bf, acc2[0][cg], 0, 0, 0);
        acc2[1][cg] = __builtin_amdgcn_mfma_f32_16x16x32_bf16(a1, bf, acc2[1][cg], 0, 0, 0);
      }
    }
  }
  __syncthreads();
  {
#pragma unroll
    for (int ro = 0; ro < 2; ++ro)
#pragma unroll
      for (int cg = 0; cg < 4; ++cg) {
        bf16x4 st;
#pragma unroll
        for (int r = 0; r < 4; ++r) {
          float v = acc2[ro][cg][r] + b2[wv * 32 + ro * 16 + lh * 4 + r];
          st[r] = (__bf16)fmaxf(v, 0.f);
        }
        *(bf16x4*)&e2T[cg * 16 + lq][wv * 32 + ro * 16 + lh * 4] = st;
      }
  }
  __syncthreads();

  {
    const float* w3r = w3 + (size_t)(wv * 16 + lq) * O_;
    s16x8 a0 = ldw_bf16(w3r + lh * 8);
    s16x8 a1 = ldw_bf16(w3r + 32 + lh * 8);
#pragma unroll
    for (int cg = 0; cg < 8; ++cg) {
      int col = cg * 16 + lq;
      int nl = col >> 3, rr = (col >> 2) & 1, kk = col & 3;
      const __bf16* base = &e2T[nl * 4 + kk][rr * 64];
      f32x4 acc = {0.f, 0.f, 0.f, 0.f};
      acc = __builtin_amdgcn_mfma_f32_16x16x32_bf16(a0, *(const s16x8*)(base + lh * 8),      acc, 0, 0, 0);
      acc = __builtin_amdgcn_mfma_f32_16x16x32_bf16(a1, *(const s16x8*)(base + 32 + lh * 8), acc, 0, 0, 0);
      float vv[4];
#pragma unroll
      for (int r = 0; r < 4; ++r) {
        float v = acc[r];
        v = fmaxf(v, __shfl_xor(v, 1));
        v = fmaxf(v, __shfl_xor(v, 2));
        vv[r] = v;
      }
      if ((lq & 3) == 0) {
        int mloc = col >> 2;
        int o = wv * 16 + lh * 4;
#pragma unroll
        for (int r = 0; r < 4; ++r) oSt[o + r][mloc] = vv[r] + b3[o + r];
      }
    }
  }
  __syncthreads();

#pragma unroll
  for (int it = 0; it < 2; ++it) {
    int u = t + it * 256;
    int o = u >> 3, seg = u & 7;
    *(float4*)&out[((size_t)b * O_ + o) * NM_ + n0 * 2 + seg * 4] =
        *(const float4*)&oSt[o][seg * 4];
  }
}

extern "C" void kernel_launch(void* const* d_in, const int* in_sizes, int n_in,
                              void* d_out, int out_size, void* d_ws, size_t ws_size,
                              hipStream_t stream) {
  const float* x  = (const float*)d_in[0];
  const float* w1 = (const float*)d_in[1];
  const float* b1 = (const float*)d_in[2];
  const float* w2 = (const float*)d_in[3];
  const float* b2 = (const float*)d_in[4];
  const float* w3 = (const float*)d_in[5];
  const float* b3 = (const float*)d_in[6];
  float* out = (float*)d_out;

  // ---- layout: [ag 24MB (xT32 @0 inside) | xh | xx | knn | wh | wg]
  // xT32 aliases ag[0..16MB): consumed by knn_mfma's fused rerank before agemm writes ag.
  const size_t AGB      = (size_t)B_ * N_ * AGC * 2;          // 25,165,824
  const size_t off_xhN  = AGB;
  const size_t off_xxN  = off_xhN + (size_t)B_ * N_ * C_ * 2;
  const size_t off_knnN = off_xxN + (size_t)B_ * N_ * 4;
  const size_t off_whN  = off_knnN + (size_t)B_ * N_ * K_ * 4;
  const size_t off_wgN  = off_whN + (size_t)61440 * 2;
  const size_t NEED_NEW = off_wgN + (size_t)AGC * 128 * 2;

  if (ws_size >= NEED_NEW) {
    u16*   agp  = (u16*)d_ws;
    float* xT32 = (float*)d_ws;                         // aliases ag[0..16MB)
    u16*   xhp  = (u16*)((char*)d_ws + off_xhN);
    float* xx   = (float*)((char*)d_ws + off_xxN);
    int*   knn  = (int*)((char*)d_ws + off_knnN);
    u16*   whp  = (u16*)((char*)d_ws + off_whN);
    u16*   wgp  = (u16*)((char*)d_ws + off_wgN);

    hipLaunchKernelGGL(prep_kernel, dim3(N_ / 64, B_ + 1), dim3(256), 0, stream,
                       x, w1, w2, w3, xT32, xhp, xx, whp, wgp);
    hipLaunchKernelGGL(knn_mfma, dim3(N_ / 128, B_), dim3(512), 0, stream,
                       xhp, xT32, xx, knn);
    hipLaunchKernelGGL(agemm_kernel, dim3(N_ / 64, B_), dim3(256), 0, stream,
                       xhp, wgp, b1, b2, agp);
    hipLaunchKernelGGL(fused_ag, dim3(N_ / 16, B_), dim3(256), 0, stream,
                       agp, whp, knn, b3, out);
  } else {
    float* xx = (float*)d_ws;
    int* knn = (int*)((char*)d_ws + (size_t)B_ * N_ * 4);
    hipLaunchKernelGGL(xx_kernel, dim3((B_ * N_) / 256), dim3(256), 0, stream, x, xx);
    hipLaunchKernelGGL(knn_kernel, dim3(N_ / 64, B_), dim3(256), 0, stream, x, xx, knn);
    hipLaunchKernelGGL(fused_fb, dim3(N_ / 16, B_), dim3(256), 0, stream,
                       x, knn, w1, b1, w2, b2, w3, b3, out);
  }
}

// Round 15
// 99.064 us; speedup vs baseline: 1.1850x; 1.1850x over previous
//
#include <hip/hip_runtime.h>
#include <cstdint>
#include <cstddef>

#define B_  16
#define C_  128
#define N_  2048
#define K_  4
#define O_  64
#define C2_ 256   // 2*C
#define ED_ 320   // 2*C + O
#define NM_ 4096  // N*R
#define AGC 384   // channels per ag row

typedef float  f32x4  __attribute__((ext_vector_type(4)));
typedef short  s16x8  __attribute__((ext_vector_type(8)));
typedef __bf16 bf16x4 __attribute__((ext_vector_type(4)));
typedef __bf16 bf16x8 __attribute__((ext_vector_type(8)));
typedef unsigned short u16;
typedef unsigned int   u32;
typedef unsigned int   u32x4 __attribute__((ext_vector_type(4)));

__device__ __forceinline__ u32 umin32(u32 a, u32 b) { return a < b ? a : b; }
__device__ __forceinline__ u32 umax32(u32 a, u32 b) { return a > b ? a : b; }
__device__ __forceinline__ float bf2f(u16 h) { return __builtin_bit_cast(float, (u32)h << 16); }

// median of 3 u32 — single VOP3; branchless depth-1 sorted insert
__device__ __forceinline__ u32 med3u(u32 v, u32 a, u32 b) {
  u32 r;
  asm("v_med3_u32 %0, %1, %2, %3" : "=v"(r) : "v"(v), "v"(a), "v"(b));
  return r;
}

__device__ __forceinline__ s16x8 ldw_bf16(const float* __restrict__ p) {
  float4 a = *(const float4*)p;
  float4 c = *(const float4*)(p + 4);
  bf16x8 r;
  r[0] = (__bf16)a.x; r[1] = (__bf16)a.y; r[2] = (__bf16)a.z; r[3] = (__bf16)a.w;
  r[4] = (__bf16)c.x; r[5] = (__bf16)c.y; r[6] = (__bf16)c.z; r[7] = (__bf16)c.w;
  return __builtin_bit_cast(s16x8, r);
}

__device__ __forceinline__ u32 relu2(u32 u) {
  u32 s = u & 0x80008000u;
  u32 m = s - (s >> 15);
  return u & ~(m | s);
}
__device__ __forceinline__ s16x8 relu8(s16x8 v) {
  u32x4 u = __builtin_bit_cast(u32x4, v);
  u[0] = relu2(u[0]); u[1] = relu2(u[1]);
  u[2] = relu2(u[2]); u[3] = relu2(u[3]);
  return __builtin_bit_cast(s16x8, u);
}

__device__ __forceinline__ void glds16(const void* g, void* l) {
  __builtin_amdgcn_global_load_lds(
      (const __attribute__((address_space(1))) u32*)g,
      (__attribute__((address_space(3))) u32*)l, 16, 0, 0);
}

// ============ prep: xx, xT32, xh (bf16 rows, chunk XOR-swizzled), wh, wg ============
__global__ __launch_bounds__(256) void prep_kernel(const float* __restrict__ x,
                                                   const float* __restrict__ w1,
                                                   const float* __restrict__ w2,
                                                   const float* __restrict__ w3,
                                                   float* __restrict__ xT32,
                                                   u16* __restrict__ xh,
                                                   float* __restrict__ xx,
                                                   u16* __restrict__ wh,
                                                   u16* __restrict__ wg) {
  const int t = threadIdx.x;
  if (blockIdx.y == B_) {
    const int gid = blockIdx.x * 256 + t;   // 0..8191
    for (int i = gid; i < 15360; i += 8192) {
      const float* src; u16* dst;
      if (i < 4096)       { src = w1 + (size_t)i * 4;            dst = wh + (size_t)i * 4; }
      else if (i < 14336) { src = w2 + (size_t)(i - 4096) * 4;   dst = wh + 16384 + (size_t)(i - 4096) * 4; }
      else                { src = w3 + (size_t)(i - 14336) * 4;  dst = wh + 57344 + (size_t)(i - 14336) * 4; }
      float4 v = *(const float4*)src;
      ushort4 h;
      h.x = __builtin_bit_cast(u16, (__bf16)v.x);
      h.y = __builtin_bit_cast(u16, (__bf16)v.y);
      h.z = __builtin_bit_cast(u16, (__bf16)v.z);
      h.w = __builtin_bit_cast(u16, (__bf16)v.w);
      *(ushort4*)dst = h;
    }
    if (wg) {
      for (int i = gid; i < 12288; i += 8192) {
        int r = i >> 5;
        int c4 = (i & 31) * 4;
        const float* src;
        if (r < 64)       src = w1 + (size_t)r * C2_ + c4;
        else if (r < 128) src = w1 + (size_t)(r - 64) * C2_ + 128 + c4;
        else if (r < 256) src = w2 + (size_t)(r - 128) * ED_ + 64 + c4;
        else              src = w2 + (size_t)(r - 256) * ED_ + 192 + c4;
        float4 v = *(const float4*)src;
        ushort4 h;
        h.x = __builtin_bit_cast(u16, (__bf16)v.x);
        h.y = __builtin_bit_cast(u16, (__bf16)v.y);
        h.z = __builtin_bit_cast(u16, (__bf16)v.z);
        h.w = __builtin_bit_cast(u16, (__bf16)v.w);
        *(ushort4*)&wg[(size_t)r * 128 + c4] = h;
      }
    }
    return;
  }

  __shared__ __align__(16) float sx[C_][65];
  const int b = blockIdx.y, n0 = blockIdx.x * 64;
  const float* xb = x + (size_t)b * C_ * N_;
  for (int u = t; u < C_ * 16; u += 256) {
    int c = u >> 4, f4 = u & 15;
    float4 v = *(const float4*)&xb[(size_t)c * N_ + n0 + f4 * 4];
    sx[c][f4 * 4 + 0] = v.x; sx[c][f4 * 4 + 1] = v.y;
    sx[c][f4 * 4 + 2] = v.z; sx[c][f4 * 4 + 3] = v.w;
  }
  __syncthreads();
  if (t < 64) {
    float s = 0.f;
    for (int c = 0; c < C_; ++c) { float v = sx[c][t]; s = fmaf(v, v, s); }
    xx[b * N_ + n0 + t] = s;
  }
  for (int u = t; u < 64 * 16; u += 256) {
    int n = u >> 4, cb = u & 15;
    float vv[8]; s16x8 hv;
#pragma unroll
    for (int j = 0; j < 8; ++j) {
      float v = sx[cb * 8 + j][n];
      vv[j] = v;
      hv[j] = (short)__builtin_bit_cast(u16, (__bf16)v);
    }
    size_t ro = ((size_t)b * N_ + n0 + n) * C_;
    *(float4*)&xT32[ro + cb * 8]     = make_float4(vv[0], vv[1], vv[2], vv[3]);
    *(float4*)&xT32[ro + cb * 8 + 4] = make_float4(vv[4], vv[5], vv[6], vv[7]);
    int sc = cb ^ (n & 7);
    *(s16x8*)&xh[ro + sc * 8] = hv;
  }
}

// ============ knn: barrier-free bf16 MFMA distances -> top-8 -> fused exact rerank ============
// m-fragments loaded global->reg directly (L2-resident); LDS for merge, then query-row
// staging (aliased over the dead merge region) + rerank scratch.
// key = bits(dd + 512) (dd >= -xx[q] -> positive -> bit-monotone), low 11 bits = idx.
__global__ __launch_bounds__(256) void knn_mfma(const u16* __restrict__ xh,
                                                const float* __restrict__ xT32,
                                                const float* __restrict__ xx,
                                                int* __restrict__ knn_out) {
  // layout (u32): [0..8448) merge(first 5440)/sq[64][132] | cim[512] | sdv[512]
  __shared__ __align__(16) u32 shm[8448 + 512 + 512];
  u32*   cd  = shm;
  float* sq  = (float*)shm;           // 64 x 132 f32, aliases merge region after use
  u32*   cim = shm + 8448;
  float* sdv = (float*)(shm + 8448 + 512);
  const int b = blockIdx.y, q0 = blockIdx.x * 64;
  const int t = threadIdx.x;
  const int wv = t >> 6, lq = t & 15, lh = (t >> 4) & 3;
  const u16* xhb = xh + (size_t)b * N_ * C_;
  const float* xxb = xx + b * N_;

  // Q fragments (B-operand), registers for the whole main loop
  s16x8 qf[4][4];
#pragma unroll
  for (int qt = 0; qt < 4; ++qt)
#pragma unroll
    for (int ks = 0; ks < 4; ++ks) {
      int q = q0 + qt * 16 + lq;
      int ch = (ks * 4 + lh) ^ (q & 7);
      qf[qt][ks] = *(const s16x8*)&xhb[(size_t)q * C_ + ch * 8];
    }

  u32 pk[4][5];   // sorted ascending per chain
#pragma unroll
  for (int qt = 0; qt < 4; ++qt)
#pragma unroll
    for (int s = 0; s < 5; ++s) pk[qt][s] = 0xFFFFFFFFu;

  const int rbase = wv * 16 + lq;
  int choff[4];
#pragma unroll
  for (int ks = 0; ks < 4; ++ks) choff[ks] = ((ks * 4 + lh) ^ (lq & 7)) * 8;

  auto loadf = [&](int step, s16x8* d) {
    const u16* rp = xhb + (size_t)(step * 64 + rbase) * C_;
#pragma unroll
    for (int ks = 0; ks < 4; ++ks) d[ks] = *(const s16x8*)&rp[choff[ks]];
  };
  auto loadxx = [&](int step) -> f32x4 {
    return *(const f32x4*)&xxb[step * 64 + wv * 16 + lh * 4];
  };
  auto dostep = [&](int step, const s16x8* mf, f32x4 xm4) {
    f32x4 acc[4];
#pragma unroll
    for (int qt = 0; qt < 4; ++qt) acc[qt] = (f32x4){0.f, 0.f, 0.f, 0.f};
#pragma unroll
    for (int ks = 0; ks < 4; ++ks)
#pragma unroll
      for (int qt = 0; qt < 4; ++qt)
        acc[qt] = __builtin_amdgcn_mfma_f32_16x16x32_bf16(mf[ks], qf[qt][ks], acc[qt], 0, 0, 0);
    const int mrow = step * 64 + wv * 16 + lh * 4;
    float xma[4] = {xm4[0] + 512.f, xm4[1] + 512.f, xm4[2] + 512.f, xm4[3] + 512.f};
#pragma unroll
    for (int r = 0; r < 4; ++r) {
#pragma unroll
      for (int qt = 0; qt < 4; ++qt) {   // independent chains, depth-1 insert
        float dd = fmaf(acc[qt][r], -2.f, xma[r]);   // dd+512 > 0 always
        u32 u = __builtin_bit_cast(u32, dd);
        u32 v = (u & 0xFFFFF800u) | (u32)(mrow + r);
        u32 n0 = umin32(v, pk[qt][0]);
        u32 n1 = med3u(v, pk[qt][0], pk[qt][1]);
        u32 n2 = med3u(v, pk[qt][1], pk[qt][2]);
        u32 n3 = med3u(v, pk[qt][2], pk[qt][3]);
        u32 n4 = med3u(v, pk[qt][3], pk[qt][4]);
        pk[qt][0] = n0; pk[qt][1] = n1; pk[qt][2] = n2;
        pk[qt][3] = n3; pk[qt][4] = n4;
      }
    }
  };

  // double-buffered in named regs (fragments AND xx prefetched one step ahead)
  s16x8 fa[4], fb[4];
  f32x4 xa, xb4;
  loadf(0, fa);
  loadf(1, fb);
  xa = loadxx(0);
  xb4 = loadxx(1);
  for (int step = 0; step < 32; step += 2) {
    dostep(step, fa, xa);
    if (step + 2 < 32) { loadf(step + 2, fa); xa = loadxx(step + 2); }
    dostep(step + 1, fb, xb4);
    if (step + 3 < 32) { loadf(step + 3, fb); xb4 = loadxx(step + 3); }
  }

  // merge: per local q, 16 units x 5 packed candidates (stride 85 - odd, no camping)
  const int unit = wv * 4 + lh;
#pragma unroll
  for (int qt = 0; qt < 4; ++qt) {
    int ql = qt * 16 + lq;
#pragma unroll
    for (int s = 0; s < 5; ++s) cd[ql * 85 + unit * 5 + s] = pk[qt][s];
  }
  __syncthreads();
  if (t < 64) {
    u32 fd[8];
#pragma unroll
    for (int s = 0; s < 8; ++s) fd[s] = 0xFFFFFFFFu;
    for (int j = 0; j < 80; ++j) {
      u32 v = cd[t * 85 + j];
      u32 m0 = umin32(v, fd[0]);
      u32 m1 = med3u(v, fd[0], fd[1]);
      u32 m2 = med3u(v, fd[1], fd[2]);
      u32 m3 = med3u(v, fd[2], fd[3]);
      u32 m4 = med3u(v, fd[3], fd[4]);
      u32 m5 = med3u(v, fd[4], fd[5]);
      u32 m6 = med3u(v, fd[5], fd[6]);
      u32 m7 = med3u(v, fd[6], fd[7]);
      fd[0] = m0; fd[1] = m1; fd[2] = m2; fd[3] = m3;
      fd[4] = m4; fd[5] = m5; fd[6] = m6; fd[7] = m7;
    }
#pragma unroll
    for (int s = 0; s < 8; ++s) cim[t * 8 + s] = fd[s] & 0x7FFu;
  }
  __syncthreads();   // merge region dead; cim live

  // ---- stage the 64 query fp32 rows into LDS (coalesced, padded stride 132) ----
  {
    const float* xb32 = xT32 + (size_t)b * N_ * C_;
    for (int u = t; u < 64 * 32; u += 256) {
      int n = u >> 5, seg = u & 31;
      *(f32x4*)&sq[n * 132 + seg * 4] =
          *(const f32x4*)&xb32[(size_t)(q0 + n) * C_ + seg * 4];
    }
  }
  __syncthreads();

  // ---- fused exact fp32 rerank of the 8 candidates (query side from LDS) ----
  {
    const float* xb32 = xT32 + (size_t)b * N_ * C_;
    const int ql = t >> 2, cs = t & 3;
    const float* qr = &sq[ql * 132];
#pragma unroll
    for (int cc = 0; cc < 2; ++cc) {
      int cslot = cs + cc * 4;
      int idx = (int)cim[ql * 8 + cslot];
      const float* mr = xb32 + (size_t)idx * C_;
      float a0 = 0.f, a1 = 0.f, a2 = 0.f, a3 = 0.f;
#pragma unroll 8
      for (int i = 0; i < 32; ++i) {
        f32x4 qv = *(const f32x4*)&qr[i * 4];
        float4 mv = *(const float4*)&mr[i * 4];
        a0 = fmaf(qv[0], mv.x, a0); a1 = fmaf(qv[1], mv.y, a1);
        a2 = fmaf(qv[2], mv.z, a2); a3 = fmaf(qv[3], mv.w, a3);
      }
      float dot = (a0 + a1) + (a2 + a3);
      sdv[ql * 8 + cslot] = xxb[idx] - 2.f * dot;
    }
  }
  __syncthreads();
  if (t < 64) {
    float dloc[8]; int iloc[8];
#pragma unroll
    for (int j = 0; j < 8; ++j) { dloc[j] = sdv[t * 8 + j]; iloc[j] = (int)cim[t * 8 + j]; }
    u32 used = 0;
#pragma unroll
    for (int s = 0; s < 4; ++s) {
      float bdv = 1e30f; int bidx = 0x7fffffff; int bj = 0;
#pragma unroll
      for (int j = 0; j < 8; ++j) {
        if (!((used >> j) & 1)) {
          bool bet = (dloc[j] < bdv) || (dloc[j] == bdv && iloc[j] < bidx);
          if (bet) { bdv = dloc[j]; bidx = iloc[j]; bj = j; }
        }
      }
      used |= 1u << bj;
      knn_out[((size_t)b * N_ + q0 + t) * K_ + s] = bidx;
    }
  }
}

// ============ agemm: ag[m][384] = wg @ [x; relu(x)] slices, biases folded ============
__global__ __launch_bounds__(256, 2) void agemm_kernel(
    const u16* __restrict__ xh, const u16* __restrict__ wg,
    const float* __restrict__ b1, const float* __restrict__ b2,
    u16* __restrict__ ag) {
  __shared__ __align__(16) char sm[66560];
  u16* outT = (u16*)(sm + 16384);
  const int b = blockIdx.y, m0 = blockIdx.x * 64;
  const int t = threadIdx.x, lane = t & 63, wv = t >> 6, lq = t & 15, lh = (t >> 4) & 3;
  const u16* xhb = xh + (size_t)b * N_ * C_;

  {
    const char* s = (const char*)(xhb + (size_t)m0 * C_);
#pragma unroll
    for (int c = 0; c < 4; ++c) {
      int off = (wv * 4 + c) * 1024;
      glds16(s + off + lane * 16, sm + off);
    }
  }

  s16x8 af[6][4];
#pragma unroll
  for (int rt = 0; rt < 6; ++rt)
#pragma unroll
    for (int ks = 0; ks < 4; ++ks)
      af[rt][ks] = *(const s16x8*)&wg[(size_t)(wv * 96 + rt * 16 + lq) * 128 + ks * 32 + lh * 8];

  f32x4 acc[6][4];
#pragma unroll
  for (int rt = 0; rt < 6; ++rt)
#pragma unroll
    for (int cg = 0; cg < 4; ++cg) acc[rt][cg] = (f32x4){0.f, 0.f, 0.f, 0.f};

  asm volatile("s_waitcnt vmcnt(0)");
  __syncthreads();

#pragma unroll
  for (int cg = 0; cg < 4; ++cg) {
    s16x8 braw[4], brel[4];
#pragma unroll
    for (int ks = 0; ks < 4; ++ks) {
      int row = cg * 16 + lq;
      braw[ks] = *(const s16x8*)(sm + row * 256 + (((ks * 4 + lh) ^ (lq & 7)) * 16));
      brel[ks] = relu8(braw[ks]);
    }
#pragma unroll
    for (int rt = 0; rt < 6; ++rt) {
      const bool rl = (wv * 96 + rt * 16) >= 128;
#pragma unroll
      for (int ks = 0; ks < 4; ++ks)
        acc[rt][cg] = __builtin_amdgcn_mfma_f32_16x16x32_bf16(
            af[rt][ks], rl ? brel[ks] : braw[ks], acc[rt][cg], 0, 0, 0);
    }
  }

#pragma unroll
  for (int rt = 0; rt < 6; ++rt) {
    const int ch0 = wv * 96 + rt * 16 + lh * 4;
    float bias[4];
#pragma unroll
    for (int r = 0; r < 4; ++r) {
      int c = ch0 + r;
      bias[r] = (c < 64) ? b1[c] : ((c >= 128 && c < 256) ? b2[c - 128] : 0.f);
    }
#pragma unroll
    for (int cg = 0; cg < 4; ++cg) {
      bf16x4 st;
#pragma unroll
      for (int r = 0; r < 4; ++r) st[r] = (__bf16)(acc[rt][cg][r] + bias[r]);
      *(bf16x4*)&outT[(size_t)(cg * 16 + lq) * 392 + ch0] = st;
    }
  }
  __syncthreads();

  {
    const int row = t >> 2, p = t & 3;
#pragma unroll
    for (int k = 0; k < 12; ++k) {
      int seg = k * 4 + p;
      *(u32x4*)&ag[((size_t)b * N_ + m0 + row) * AGC + seg * 8] =
          *(const u32x4*)&outT[(size_t)row * 392 + seg * 8];
    }
  }
}

// ============ fused_ag: gathers of precomputed ag + small GEMMs ============
__global__ __launch_bounds__(256, 3) void fused_ag(
    const u16* __restrict__ ag, const u16* __restrict__ wh,
    const int* __restrict__ knn_idx,
    const float* __restrict__ b3, float* __restrict__ out) {
  __shared__ __align__(16) char fsm[44032];
  u16* e1T = (u16*)fsm;
  u16* s2T = (u16*)(fsm + 9216);
  u16* e2T = (u16*)(fsm + 26624);
  float* oSt = (float*)fsm;   // [64][36], aliases e1T after p2 frag reads

  const int t = threadIdx.x, wv = t >> 6, lq = t & 15, lh = (t >> 4) & 3;
  const int b = blockIdx.y, n0 = blockIdx.x * 16;
  const u16* agb = ag + (size_t)b * N_ * AGC;
  const u16* w2h = wh + 16384;   // [128][320]
  const u16* w3h = wh + 57344;   // [64][64]

  s16x8 w2f[2][2];
#pragma unroll
  for (int rt = 0; rt < 2; ++rt)
#pragma unroll
    for (int ks = 0; ks < 2; ++ks)
      w2f[rt][ks] = *(const s16x8*)&w2h[(size_t)(wv * 32 + rt * 16 + lq) * ED_ + ks * 32 + lh * 8];
  const s16x8 w3a = *(const s16x8*)&w3h[(size_t)(wv * 16 + lq) * O_ + lh * 8];
  const s16x8 w3b = *(const s16x8*)&w3h[(size_t)(wv * 16 + lq) * O_ + 32 + lh * 8];
  const float4 b3v = *(const float4*)&b3[wv * 16 + lh * 4];

  {
    const int col = t >> 2, p = t & 3;
    const int n = n0 + (col >> 2);
    const int nid = knn_idx[((size_t)b * N_ + n) * K_ + (col & 3)];
    const u16* rc = agb + (size_t)n * AGC;
    const u16* rn = agb + (size_t)nid * AGC;
#pragma unroll
    for (int q = 0; q < 2; ++q) {
      s16x8 va = *(const s16x8*)&rc[p * 16 + q * 8];
      s16x8 vb = *(const s16x8*)&rn[64 + p * 16 + q * 8];
      bf16x8 r;
#pragma unroll
      for (int j = 0; j < 8; ++j)
        r[j] = (__bf16)fmaxf(bf2f((u16)va[j]) + bf2f((u16)vb[j]), 0.f);
      *(bf16x8*)&e1T[(size_t)col * 72 + p * 16 + q * 8] = r;
    }
#pragma unroll
    for (int q = 0; q < 4; ++q) {
      s16x8 va = *(const s16x8*)&rc[128 + p * 32 + q * 8];
      s16x8 vb = *(const s16x8*)&rn[256 + p * 32 + q * 8];
      bf16x8 r;
#pragma unroll
      for (int j = 0; j < 8; ++j)
        r[j] = (__bf16)(bf2f((u16)va[j]) + bf2f((u16)vb[j]));
      *(bf16x8*)&s2T[(size_t)col * 136 + p * 32 + q * 8] = r;
    }
  }
  __syncthreads();   // B1

  {
    f32x4 acc[2][4];
#pragma unroll
    for (int rt = 0; rt < 2; ++rt)
#pragma unroll
      for (int cg = 0; cg < 4; ++cg) acc[rt][cg] = (f32x4){0.f, 0.f, 0.f, 0.f};
#pragma unroll
    for (int ks = 0; ks < 2; ++ks)
#pragma unroll
      for (int cg = 0; cg < 4; ++cg) {
        s16x8 bf = *(const s16x8*)&e1T[(size_t)(cg * 16 + lq) * 72 + ks * 32 + lh * 8];
#pragma unroll
        for (int rt = 0; rt < 2; ++rt)
          acc[rt][cg] = __builtin_amdgcn_mfma_f32_16x16x32_bf16(w2f[rt][ks], bf, acc[rt][cg], 0, 0, 0);
      }
#pragma unroll
    for (int rt = 0; rt < 2; ++rt)
#pragma unroll
      for (int cg = 0; cg < 4; ++cg) {
        const int col = cg * 16 + lq;
        const int j0 = wv * 32 + rt * 16 + lh * 4;
        ushort4 sv = *(const ushort4*)&s2T[(size_t)col * 136 + j0];
        bf16x4 st;
        st[0] = (__bf16)fmaxf(acc[rt][cg][0] + bf2f(sv.x), 0.f);
        st[1] = (__bf16)fmaxf(acc[rt][cg][1] + bf2f(sv.y), 0.f);
        st[2] = (__bf16)fmaxf(acc[rt][cg][2] + bf2f(sv.z), 0.f);
        st[3] = (__bf16)fmaxf(acc[rt][cg][3] + bf2f(sv.w), 0.f);
        *(bf16x4*)&e2T[(size_t)col * 136 + j0] = st;
      }
  }
  __syncthreads();   // B2

  {
#pragma unroll
    for (int cg = 0; cg < 8; ++cg) {
      int col = cg * 16 + lq;
      int nl = col >> 3, rr = (col >> 2) & 1, kk = col & 3;
      int row = nl * 4 + kk;
      s16x8 f1 = *(const s16x8*)&e2T[(size_t)row * 136 + rr * 64 + lh * 8];
      s16x8 f2 = *(const s16x8*)&e2T[(size_t)row * 136 + rr * 64 + 32 + lh * 8];
      f32x4 acc = {0.f, 0.f, 0.f, 0.f};
      acc = __builtin_amdgcn_mfma_f32_16x16x32_bf16(w3a, f1, acc, 0, 0, 0);
      acc = __builtin_amdgcn_mfma_f32_16x16x32_bf16(w3b, f2, acc, 0, 0, 0);
      float vv[4];
#pragma unroll
      for (int r = 0; r < 4; ++r) {
        float v = acc[r];
        v = fmaxf(v, __shfl_xor(v, 1));
        v = fmaxf(v, __shfl_xor(v, 2));
        vv[r] = v;
      }
      if ((lq & 3) == 0) {
        int mloc = col >> 2;
        int o = wv * 16 + lh * 4;
        const float b3a[4] = {b3v.x, b3v.y, b3v.z, b3v.w};
#pragma unroll
        for (int r = 0; r < 4; ++r) oSt[(size_t)(o + r) * 36 + mloc] = vv[r] + b3a[r];
      }
    }
  }
  __syncthreads();   // B3

#pragma unroll
  for (int io = 0; io < 2; ++io) {
    int u = t + io * 256;
    int o = u >> 3, seg = u & 7;
    *(float4*)&out[((size_t)b * O_ + o) * NM_ + n0 * 2 + seg * 4] =
        *(const float4*)&oSt[(size_t)o * 36 + seg * 4];
  }
}

// ============ slow fallback kernels ============
__global__ __launch_bounds__(256) void xx_kernel(const float* __restrict__ x,
                                                 float* __restrict__ xx) {
  int g = blockIdx.x * 256 + threadIdx.x;
  int b = g >> 11;
  int n = g & (N_ - 1);
  const float* xp = x + (size_t)b * C_ * N_ + n;
  float s = 0.f;
#pragma unroll 8
  for (int c = 0; c < C_; ++c) { float v = xp[(size_t)c * N_]; s += v * v; }
  xx[g] = s;
}

__global__ __launch_bounds__(256) void knn_kernel(const float* __restrict__ x,
                                                  const float* __restrict__ xx,
                                                  int* __restrict__ knn_out) {
  __shared__ __align__(16) float qT[C_ * 64];
  __shared__ __align__(16) float mT[C_ * 64];
  const int b = blockIdx.y;
  const int q0 = blockIdx.x * 64;
  const int t = threadIdx.x;
  const float* xb = x + (size_t)b * C_ * N_;
  const float* xxb = xx + b * N_;
  for (int i = t; i < C_ * 64; i += 256) {
    int c = i >> 6, q = i & 63;
    qT[i] = xb[(size_t)c * N_ + q0 + q];
  }
  const int tq = t & 15;
  const int tm = t >> 4;
  float bd[4][4]; int bi[4][4];
#pragma unroll
  for (int a = 0; a < 4; ++a)
#pragma unroll
    for (int s = 0; s < 4; ++s) { bd[a][s] = 1e30f; bi[a][s] = 0; }
  for (int m0 = 0; m0 < N_; m0 += 64) {
    __syncthreads();
    for (int i = t; i < C_ * 64; i += 256) {
      int c = i >> 6, m = i & 63;
      mT[i] = xb[(size_t)c * N_ + m0 + m];
    }
    __syncthreads();
    float acc[4][4];
#pragma unroll
    for (int a = 0; a < 4; ++a)
#pragma unroll
      for (int j = 0; j < 4; ++j) acc[a][j] = 0.f;
#pragma unroll 4
    for (int c = 0; c < C_; ++c) {
      float4 qv = *(const float4*)&qT[c * 64 + tq * 4];
      float4 mv = *(const float4*)&mT[c * 64 + tm * 4];
      float qa[4] = {qv.x, qv.y, qv.z, qv.w};
      float ma[4] = {mv.x, mv.y, mv.z, mv.w};
#pragma unroll
      for (int a = 0; a < 4; ++a)
#pragma unroll
        for (int j = 0; j < 4; ++j) acc[a][j] += qa[a] * ma[j];
    }
#pragma unroll
    for (int j = 0; j < 4; ++j) {
      float xm = xxb[m0 + tm * 4 + j];
      int id = m0 + tm * 4 + j;
#pragma unroll
      for (int a = 0; a < 4; ++a) {
        float d = xm - 2.f * acc[a][j];
        if (d < bd[a][3]) {
          bd[a][3] = d; bi[a][3] = id;
#pragma unroll
          for (int s = 3; s > 0; --s)
            if (bd[a][s] < bd[a][s - 1]) {
              float td = bd[a][s]; bd[a][s] = bd[a][s - 1]; bd[a][s - 1] = td;
              int ti = bi[a][s]; bi[a][s] = bi[a][s - 1]; bi[a][s - 1] = ti;
            }
        }
      }
    }
  }
  __syncthreads();
  float* cd = qT;
  int* ci = (int*)mT;
#pragma unroll
  for (int a = 0; a < 4; ++a) {
    int q = tq * 4 + a;
#pragma unroll
    for (int s = 0; s < 4; ++s) {
      cd[q * 64 + tm * 4 + s] = bd[a][s];
      ci[q * 64 + tm * 4 + s] = bi[a][s];
    }
  }
  __syncthreads();
  if (t < 64) {
    float fd[4]; int fi[4];
#pragma unroll
    for (int s = 0; s < 4; ++s) { fd[s] = 1e30f; fi[s] = 0; }
    for (int j = 0; j < 64; ++j) {
      float d = cd[t * 64 + j];
      int id = ci[t * 64 + j];
      if (d < fd[3]) {
        fd[3] = d; fi[3] = id;
#pragma unroll
        for (int s = 3; s > 0; --s)
          if (fd[s] < fd[s - 1]) {
            float td = fd[s]; fd[s] = fd[s - 1]; fd[s - 1] = td;
            int ti = fi[s]; fi[s] = fi[s - 1]; fi[s - 1] = ti;
          }
      }
    }
#pragma unroll
    for (int s = 0; s < 4; ++s)
      knn_out[(b * N_ + q0 + t) * K_ + s] = fi[s];
  }
}

__global__ __launch_bounds__(256, 5) void fused_fb(
    const float* __restrict__ x, const int* __restrict__ knn_idx,
    const float* __restrict__ w1, const float* __restrict__ b1,
    const float* __restrict__ w2, const float* __restrict__ b2,
    const float* __restrict__ w3, const float* __restrict__ b3,
    float* __restrict__ out) {
  __shared__ __align__(16) char fsm[30976];
  __bf16 (*cT)[136]  = (__bf16(*)[136])(fsm);
  __bf16 (*e1T)[72]  = (__bf16(*)[72])(fsm + 4352);
  float  (*oSt)[36]  = (float(*)[36])(fsm + 4352);
  __bf16 (*nT)[136]  = (__bf16(*)[136])(fsm + 13568);
  __bf16 (*e2T)[136] = (__bf16(*)[136])(fsm + 13568);

  const int b  = blockIdx.y;
  const int n0 = blockIdx.x * 16;
  const int t  = threadIdx.x;
  const float* xb = x + (size_t)b * C_ * N_;

  {
    const int stn = t >> 4, stc = t & 15;
    const int kbase = (b * N_ + n0) * K_;
    const float* srcc = xb + (size_t)(stc * 8) * N_ + n0 + stn;
    bf16x8 raw;
#pragma unroll
    for (int j = 0; j < 8; ++j) raw[j] = (__bf16)srcc[(size_t)j * N_];
    *(bf16x8*)&cT[stn][stc * 8] = raw;
#pragma unroll
    for (int it = 0; it < 4; ++it) {
      int col = stn + 16 * it;
      int nid = knn_idx[kbase + col];
      const float* src = xb + (size_t)(stc * 8) * N_ + nid;
      bf16x8 rw;
#pragma unroll
      for (int j = 0; j < 8; ++j) rw[j] = (__bf16)src[(size_t)j * N_];
      *(bf16x8*)&nT[col][stc * 8] = rw;
    }
  }
  __syncthreads();

  const int lq = t & 15;
  const int lh = (t >> 4) & 3;
  const int wv = t >> 6;

  {
    const float* w1r = w1 + (size_t)(wv * 16 + lq) * C2_;
    f32x4 acc[4];
#pragma unroll
    for (int cg = 0; cg < 4; ++cg) acc[cg] = (f32x4){0.f, 0.f, 0.f, 0.f};
#pragma unroll
    for (int ks = 0; ks < 8; ++ks) {
      s16x8 a = ldw_bf16(w1r + ks * 32 + lh * 8);
#pragma unroll
      for (int cg = 0; cg < 4; ++cg) {
        const __bf16* bp = (ks < 4)
            ? &cT[cg * 4 + (lq >> 2)][ks * 32 + lh * 8]
            : &nT[cg * 16 + lq][(ks - 4) * 32 + lh * 8];
        acc[cg] = __builtin_amdgcn_mfma_f32_16x16x32_bf16(
            a, *(const s16x8*)bp, acc[cg], 0, 0, 0);
      }
    }
#pragma unroll
    for (int cg = 0; cg < 4; ++cg) {
      bf16x4 st;
#pragma unroll
      for (int r = 0; r < 4; ++r) {
        float v = acc[cg][r] + b1[wv * 16 + lh * 4 + r];
        st[r] = (__bf16)fmaxf(v, 0.f);
      }
      *(bf16x4*)&e1T[cg * 16 + lq][wv * 16 + lh * 4] = st;
    }
  }
  __syncthreads();

  f32x4 acc2[2][4];
  {
    const float* w2r0 = w2 + (size_t)(wv * 32 + lq) * ED_;
    const float* w2r1 = w2r0 + (size_t)16 * ED_;
#pragma unroll
    for (int ro = 0; ro < 2; ++ro)
#pragma unroll
      for (int cg = 0; cg < 4; ++cg) acc2[ro][cg] = (f32x4){0.f, 0.f, 0.f, 0.f};
#pragma unroll
    for (int ks = 0; ks < 10; ++ks) {
      s16x8 a0 = ldw_bf16(w2r0 + ks * 32 + lh * 8);
      s16x8 a1 = ldw_bf16(w2r1 + ks * 32 + lh * 8);
#pragma unroll
      for (int cg = 0; cg < 4; ++cg) {
        s16x8 bf;
        if (ks < 2)      bf = *(const s16x8*)&e1T[cg * 16 + lq][ks * 32 + lh * 8];
        else if (ks < 6) bf = relu8(*(const s16x8*)&cT[cg * 4 + (lq >> 2)][(ks - 2) * 32 + lh * 8]);
        else             bf = relu8(*(const s16x8*)&nT[cg * 16 + lq][(ks - 6) * 32 + lh * 8]);
        acc2[0][cg] = __builtin_amdgcn_mfma_f32_16x16x32_bf16(a0, bf, acc2[0][cg], 0, 0, 0);
        acc2[1][cg] = __builtin_amdgcn_mfma_f32_16x16x32_bf16(a1, bf, acc2[1][cg], 0, 0, 0);
      }
    }
  }
  __syncthreads();
  {
#pragma unroll
    for (int ro = 0; ro < 2; ++ro)
#pragma unroll
      for (int cg = 0; cg < 4; ++cg) {
        bf16x4 st;
#pragma unroll
        for (int r = 0; r < 4; ++r) {
          float v = acc2[ro][cg][r] + b2[wv * 32 + ro * 16 + lh * 4 + r];
          st[r] = (__bf16)fmaxf(v, 0.f);
        }
        *(bf16x4*)&e2T[cg * 16 + lq][wv * 32 + ro * 16 + lh * 4] = st;
      }
  }
  __syncthreads();

  {
    const float* w3r = w3 + (size_t)(wv * 16 + lq) * O_;
    s16x8 a0 = ldw_bf16(w3r + lh * 8);
    s16x8 a1 = ldw_bf16(w3r + 32 + lh * 8);
#pragma unroll
    for (int cg = 0; cg < 8; ++cg) {
      int col = cg * 16 + lq;
      int nl = col >> 3, rr = (col >> 2) & 1, kk = col & 3;
      const __bf16* base = &e2T[nl * 4 + kk][rr * 64];
      f32x4 acc = {0.f, 0.f, 0.f, 0.f};
      acc = __builtin_amdgcn_mfma_f32_16x16x32_bf16(a0, *(const s16x8*)(base + lh * 8),      acc, 0, 0, 0);
      acc = __builtin_amdgcn_mfma_f32_16x16x32_bf16(a1, *(const s16x8*)(base + 32 + lh * 8), acc, 0, 0, 0);
      float vv[4];
#pragma unroll
      for (int r = 0; r < 4; ++r) {
        float v = acc[r];
        v = fmaxf(v, __shfl_xor(v, 1));
        v = fmaxf(v, __shfl_xor(v, 2));
        vv[r] = v;
      }
      if ((lq & 3) == 0) {
        int mloc = col >> 2;
        int o = wv * 16 + lh * 4;
#pragma unroll
        for (int r = 0; r < 4; ++r) oSt[o + r][mloc] = vv[r] + b3[o + r];
      }
    }
  }
  __syncthreads();

#pragma unroll
  for (int it = 0; it < 2; ++it) {
    int u = t + it * 256;
    int o = u >> 3, seg = u & 7;
    *(float4*)&out[((size_t)b * O_ + o) * NM_ + n0 * 2 + seg * 4] =
        *(const float4*)&oSt[o][seg * 4];
  }
}

extern "C" void kernel_launch(void* const* d_in, const int* in_sizes, int n_in,
                              void* d_out, int out_size, void* d_ws, size_t ws_size,
                              hipStream_t stream) {
  const float* x  = (const float*)d_in[0];
  const float* w1 = (const float*)d_in[1];
  const float* b1 = (const float*)d_in[2];
  const float* w2 = (const float*)d_in[3];
  const float* b2 = (const float*)d_in[4];
  const float* w3 = (const float*)d_in[5];
  const float* b3 = (const float*)d_in[6];
  float* out = (float*)d_out;

  // ---- layout: [ag 24MB (xT32 @0 inside) | xh | xx | knn | wh | wg]
  // xT32 aliases ag[0..16MB): consumed by knn_mfma's fused rerank before agemm writes ag.
  const size_t AGB      = (size_t)B_ * N_ * AGC * 2;          // 25,165,824
  const size_t off_xhN  = AGB;
  const size_t off_xxN  = off_xhN + (size_t)B_ * N_ * C_ * 2;
  const size_t off_knnN = off_xxN + (size_t)B_ * N_ * 4;
  const size_t off_whN  = off_knnN + (size_t)B_ * N_ * K_ * 4;
  const size_t off_wgN  = off_whN + (size_t)61440 * 2;
  const size_t NEED_NEW = off_wgN + (size_t)AGC * 128 * 2;

  if (ws_size >= NEED_NEW) {
    u16*   agp  = (u16*)d_ws;
    float* xT32 = (float*)d_ws;                         // aliases ag[0..16MB)
    u16*   xhp  = (u16*)((char*)d_ws + off_xhN);
    float* xx   = (float*)((char*)d_ws + off_xxN);
    int*   knn  = (int*)((char*)d_ws + off_knnN);
    u16*   whp  = (u16*)((char*)d_ws + off_whN);
    u16*   wgp  = (u16*)((char*)d_ws + off_wgN);

    hipLaunchKernelGGL(prep_kernel, dim3(N_ / 64, B_ + 1), dim3(256), 0, stream,
                       x, w1, w2, w3, xT32, xhp, xx, whp, wgp);
    hipLaunchKernelGGL(knn_mfma, dim3(N_ / 64, B_), dim3(256), 0, stream,
                       xhp, xT32, xx, knn);
    hipLaunchKernelGGL(agemm_kernel, dim3(N_ / 64, B_), dim3(256), 0, stream,
                       xhp, wgp, b1, b2, agp);
    hipLaunchKernelGGL(fused_ag, dim3(N_ / 16, B_), dim3(256), 0, stream,
                       agp, whp, knn, b3, out);
  } else {
    float* xx = (float*)d_ws;
    int* knn = (int*)((char*)d_ws + (size_t)B_ * N_ * 4);
    hipLaunchKernelGGL(xx_kernel, dim3((B_ * N_) / 256), dim3(256), 0, stream, x, xx);
    hipLaunchKernelGGL(knn_kernel, dim3(N_ / 64, B_), dim3(256), 0, stream, x, xx, knn);
    hipLaunchKernelGGL(fused_fb, dim3(N_ / 16, B_), dim3(256), 0, stream,
                       x, knn, w1, b1, w2, b2, w3, b3, out);
  }
}

// Round 16
// 98.319 us; speedup vs baseline: 1.1940x; 1.0076x over previous
//
#include <hip/hip_runtime.h>
#include <cstdint>
#include <cstddef>

#define B_  16
#define C_  128
#define N_  2048
#define K_  4
#define O_  64
#define C2_ 256   // 2*C
#define ED_ 320   // 2*C + O
#define NM_ 4096  // N*R
#define AGC 384   // channels per ag row

typedef float  f32x4  __attribute__((ext_vector_type(4)));
typedef short  s16x8  __attribute__((ext_vector_type(8)));
typedef __bf16 bf16x4 __attribute__((ext_vector_type(4)));
typedef __bf16 bf16x8 __attribute__((ext_vector_type(8)));
typedef unsigned short u16;
typedef unsigned int   u32;
typedef unsigned int   u32x4 __attribute__((ext_vector_type(4)));

__device__ __forceinline__ u32 umin32(u32 a, u32 b) { return a < b ? a : b; }
__device__ __forceinline__ u32 umax32(u32 a, u32 b) { return a > b ? a : b; }
__device__ __forceinline__ float bf2f(u16 h) { return __builtin_bit_cast(float, (u32)h << 16); }

// median of 3 u32 — single VOP3; branchless depth-1 sorted insert
__device__ __forceinline__ u32 med3u(u32 v, u32 a, u32 b) {
  u32 r;
  asm("v_med3_u32 %0, %1, %2, %3" : "=v"(r) : "v"(v), "v"(a), "v"(b));
  return r;
}

__device__ __forceinline__ s16x8 ldw_bf16(const float* __restrict__ p) {
  float4 a = *(const float4*)p;
  float4 c = *(const float4*)(p + 4);
  bf16x8 r;
  r[0] = (__bf16)a.x; r[1] = (__bf16)a.y; r[2] = (__bf16)a.z; r[3] = (__bf16)a.w;
  r[4] = (__bf16)c.x; r[5] = (__bf16)c.y; r[6] = (__bf16)c.z; r[7] = (__bf16)c.w;
  return __builtin_bit_cast(s16x8, r);
}

__device__ __forceinline__ u32 relu2(u32 u) {
  u32 s = u & 0x80008000u;
  u32 m = s - (s >> 15);
  return u & ~(m | s);
}
__device__ __forceinline__ s16x8 relu8(s16x8 v) {
  u32x4 u = __builtin_bit_cast(u32x4, v);
  u[0] = relu2(u[0]); u[1] = relu2(u[1]);
  u[2] = relu2(u[2]); u[3] = relu2(u[3]);
  return __builtin_bit_cast(s16x8, u);
}

__device__ __forceinline__ void glds16(const void* g, void* l) {
  __builtin_amdgcn_global_load_lds(
      (const __attribute__((address_space(1))) u32*)g,
      (__attribute__((address_space(3))) u32*)l, 16, 0, 0);
}

// ============ prep: xx, xT32, xh (bf16 rows, chunk XOR-swizzled), wh, wg ============
__global__ __launch_bounds__(256) void prep_kernel(const float* __restrict__ x,
                                                   const float* __restrict__ w1,
                                                   const float* __restrict__ w2,
                                                   const float* __restrict__ w3,
                                                   float* __restrict__ xT32,
                                                   u16* __restrict__ xh,
                                                   float* __restrict__ xx,
                                                   u16* __restrict__ wh,
                                                   u16* __restrict__ wg) {
  const int t = threadIdx.x;
  if (blockIdx.y == B_) {
    const int gid = blockIdx.x * 256 + t;   // 0..8191
    for (int i = gid; i < 15360; i += 8192) {
      const float* src; u16* dst;
      if (i < 4096)       { src = w1 + (size_t)i * 4;            dst = wh + (size_t)i * 4; }
      else if (i < 14336) { src = w2 + (size_t)(i - 4096) * 4;   dst = wh + 16384 + (size_t)(i - 4096) * 4; }
      else                { src = w3 + (size_t)(i - 14336) * 4;  dst = wh + 57344 + (size_t)(i - 14336) * 4; }
      float4 v = *(const float4*)src;
      ushort4 h;
      h.x = __builtin_bit_cast(u16, (__bf16)v.x);
      h.y = __builtin_bit_cast(u16, (__bf16)v.y);
      h.z = __builtin_bit_cast(u16, (__bf16)v.z);
      h.w = __builtin_bit_cast(u16, (__bf16)v.w);
      *(ushort4*)dst = h;
    }
    if (wg) {
      for (int i = gid; i < 12288; i += 8192) {
        int r = i >> 5;
        int c4 = (i & 31) * 4;
        const float* src;
        if (r < 64)       src = w1 + (size_t)r * C2_ + c4;
        else if (r < 128) src = w1 + (size_t)(r - 64) * C2_ + 128 + c4;
        else if (r < 256) src = w2 + (size_t)(r - 128) * ED_ + 64 + c4;
        else              src = w2 + (size_t)(r - 256) * ED_ + 192 + c4;
        float4 v = *(const float4*)src;
        ushort4 h;
        h.x = __builtin_bit_cast(u16, (__bf16)v.x);
        h.y = __builtin_bit_cast(u16, (__bf16)v.y);
        h.z = __builtin_bit_cast(u16, (__bf16)v.z);
        h.w = __builtin_bit_cast(u16, (__bf16)v.w);
        *(ushort4*)&wg[(size_t)r * 128 + c4] = h;
      }
    }
    return;
  }

  __shared__ __align__(16) float sx[C_][65];
  const int b = blockIdx.y, n0 = blockIdx.x * 64;
  const float* xb = x + (size_t)b * C_ * N_;
  for (int u = t; u < C_ * 16; u += 256) {
    int c = u >> 4, f4 = u & 15;
    float4 v = *(const float4*)&xb[(size_t)c * N_ + n0 + f4 * 4];
    sx[c][f4 * 4 + 0] = v.x; sx[c][f4 * 4 + 1] = v.y;
    sx[c][f4 * 4 + 2] = v.z; sx[c][f4 * 4 + 3] = v.w;
  }
  __syncthreads();
  if (t < 64) {
    float s = 0.f;
    for (int c = 0; c < C_; ++c) { float v = sx[c][t]; s = fmaf(v, v, s); }
    xx[b * N_ + n0 + t] = s;
  }
  for (int u = t; u < 64 * 16; u += 256) {
    int n = u >> 4, cb = u & 15;
    float vv[8]; s16x8 hv;
#pragma unroll
    for (int j = 0; j < 8; ++j) {
      float v = sx[cb * 8 + j][n];
      vv[j] = v;
      hv[j] = (short)__builtin_bit_cast(u16, (__bf16)v);
    }
    size_t ro = ((size_t)b * N_ + n0 + n) * C_;
    *(float4*)&xT32[ro + cb * 8]     = make_float4(vv[0], vv[1], vv[2], vv[3]);
    *(float4*)&xT32[ro + cb * 8 + 4] = make_float4(vv[4], vv[5], vv[6], vv[7]);
    int sc = cb ^ (n & 7);
    *(s16x8*)&xh[ro + sc * 8] = hv;
  }
}

// ============ knn: barrier-free bf16 MFMA distances -> top-8 -> fused exact rerank ============
// m-fragments loaded global->reg, 4-deep prefetch pipeline (~800 cyc ahead, covers
// HBM-miss latency). LDS for merge, then query-row staging + rerank scratch.
// key = bits(dd + 512) (dd >= -xx[q] -> positive -> bit-monotone), low 11 bits = idx.
__global__ __launch_bounds__(256) void knn_mfma(const u16* __restrict__ xh,
                                                const float* __restrict__ xT32,
                                                const float* __restrict__ xx,
                                                int* __restrict__ knn_out) {
  // layout (u32): [0..8448) merge(first 5440)/sq[64][132] | cim[512] | sdv[512]
  __shared__ __align__(16) u32 shm[8448 + 512 + 512];
  u32*   cd  = shm;
  float* sq  = (float*)shm;           // 64 x 132 f32, aliases merge region after use
  u32*   cim = shm + 8448;
  float* sdv = (float*)(shm + 8448 + 512);
  const int b = blockIdx.y, q0 = blockIdx.x * 64;
  const int t = threadIdx.x;
  const int wv = t >> 6, lq = t & 15, lh = (t >> 4) & 3;
  const u16* xhb = xh + (size_t)b * N_ * C_;
  const float* xxb = xx + b * N_;

  // Q fragments (B-operand), registers for the whole main loop
  s16x8 qf[4][4];
#pragma unroll
  for (int qt = 0; qt < 4; ++qt)
#pragma unroll
    for (int ks = 0; ks < 4; ++ks) {
      int q = q0 + qt * 16 + lq;
      int ch = (ks * 4 + lh) ^ (q & 7);
      qf[qt][ks] = *(const s16x8*)&xhb[(size_t)q * C_ + ch * 8];
    }

  u32 pk[4][5];   // sorted ascending per chain
#pragma unroll
  for (int qt = 0; qt < 4; ++qt)
#pragma unroll
    for (int s = 0; s < 5; ++s) pk[qt][s] = 0xFFFFFFFFu;

  const int rbase = wv * 16 + lq;
  int choff[4];
#pragma unroll
  for (int ks = 0; ks < 4; ++ks) choff[ks] = ((ks * 4 + lh) ^ (lq & 7)) * 8;

  auto loadf = [&](int step, s16x8* d) {
    const u16* rp = xhb + (size_t)(step * 64 + rbase) * C_;
#pragma unroll
    for (int ks = 0; ks < 4; ++ks) d[ks] = *(const s16x8*)&rp[choff[ks]];
  };
  auto loadxx = [&](int step) -> f32x4 {
    return *(const f32x4*)&xxb[step * 64 + wv * 16 + lh * 4];
  };
  auto dostep = [&](int step, const s16x8* mf, f32x4 xm4) {
    f32x4 acc[4];
#pragma unroll
    for (int qt = 0; qt < 4; ++qt) acc[qt] = (f32x4){0.f, 0.f, 0.f, 0.f};
#pragma unroll
    for (int ks = 0; ks < 4; ++ks)
#pragma unroll
      for (int qt = 0; qt < 4; ++qt)
        acc[qt] = __builtin_amdgcn_mfma_f32_16x16x32_bf16(mf[ks], qf[qt][ks], acc[qt], 0, 0, 0);
    const int mrow = step * 64 + wv * 16 + lh * 4;
    float xma[4] = {xm4[0] + 512.f, xm4[1] + 512.f, xm4[2] + 512.f, xm4[3] + 512.f};
#pragma unroll
    for (int r = 0; r < 4; ++r) {
#pragma unroll
      for (int qt = 0; qt < 4; ++qt) {   // independent chains, depth-1 insert
        float dd = fmaf(acc[qt][r], -2.f, xma[r]);   // dd+512 > 0 always
        u32 u = __builtin_bit_cast(u32, dd);
        u32 v = (u & 0xFFFFF800u) | (u32)(mrow + r);
        u32 n0 = umin32(v, pk[qt][0]);
        u32 n1 = med3u(v, pk[qt][0], pk[qt][1]);
        u32 n2 = med3u(v, pk[qt][1], pk[qt][2]);
        u32 n3 = med3u(v, pk[qt][2], pk[qt][3]);
        u32 n4 = med3u(v, pk[qt][3], pk[qt][4]);
        pk[qt][0] = n0; pk[qt][1] = n1; pk[qt][2] = n2;
        pk[qt][3] = n3; pk[qt][4] = n4;
      }
    }
  };

  // 4-deep prefetch pipeline in named regs (rule #20: no runtime-indexed frag arrays)
  s16x8 fa[4], fb[4], fc[4], fd4[4];
  f32x4 xa, xb4, xc4, xd4;
  loadf(0, fa);  xa  = loadxx(0);
  loadf(1, fb);  xb4 = loadxx(1);
  loadf(2, fc);  xc4 = loadxx(2);
  loadf(3, fd4); xd4 = loadxx(3);
  for (int step = 0; step < 32; step += 4) {
    dostep(step, fa, xa);
    if (step + 4 < 32) { loadf(step + 4, fa); xa = loadxx(step + 4); }
    dostep(step + 1, fb, xb4);
    if (step + 5 < 32) { loadf(step + 5, fb); xb4 = loadxx(step + 5); }
    dostep(step + 2, fc, xc4);
    if (step + 6 < 32) { loadf(step + 6, fc); xc4 = loadxx(step + 6); }
    dostep(step + 3, fd4, xd4);
    if (step + 7 < 32) { loadf(step + 7, fd4); xd4 = loadxx(step + 7); }
  }

  // merge: per local q, 16 units x 5 packed candidates (stride 85 - odd, no camping)
  const int unit = wv * 4 + lh;
#pragma unroll
  for (int qt = 0; qt < 4; ++qt) {
    int ql = qt * 16 + lq;
#pragma unroll
    for (int s = 0; s < 5; ++s) cd[ql * 85 + unit * 5 + s] = pk[qt][s];
  }
  __syncthreads();
  if (t < 64) {
    u32 fd[8];
#pragma unroll
    for (int s = 0; s < 8; ++s) fd[s] = 0xFFFFFFFFu;
    for (int j = 0; j < 80; ++j) {
      u32 v = cd[t * 85 + j];
      u32 m0 = umin32(v, fd[0]);
      u32 m1 = med3u(v, fd[0], fd[1]);
      u32 m2 = med3u(v, fd[1], fd[2]);
      u32 m3 = med3u(v, fd[2], fd[3]);
      u32 m4 = med3u(v, fd[3], fd[4]);
      u32 m5 = med3u(v, fd[4], fd[5]);
      u32 m6 = med3u(v, fd[5], fd[6]);
      u32 m7 = med3u(v, fd[6], fd[7]);
      fd[0] = m0; fd[1] = m1; fd[2] = m2; fd[3] = m3;
      fd[4] = m4; fd[5] = m5; fd[6] = m6; fd[7] = m7;
    }
#pragma unroll
    for (int s = 0; s < 8; ++s) cim[t * 8 + s] = fd[s] & 0x7FFu;
  }
  __syncthreads();   // merge region dead; cim live

  // ---- stage the 64 query fp32 rows into LDS (coalesced, padded stride 132) ----
  {
    const float* xb32 = xT32 + (size_t)b * N_ * C_;
    for (int u = t; u < 64 * 32; u += 256) {
      int n = u >> 5, seg = u & 31;
      *(f32x4*)&sq[n * 132 + seg * 4] =
          *(const f32x4*)&xb32[(size_t)(q0 + n) * C_ + seg * 4];
    }
  }
  __syncthreads();

  // ---- fused exact fp32 rerank of the 8 candidates (query side from LDS) ----
  {
    const float* xb32 = xT32 + (size_t)b * N_ * C_;
    const int ql = t >> 2, cs = t & 3;
    const float* qr = &sq[ql * 132];
#pragma unroll
    for (int cc = 0; cc < 2; ++cc) {
      int cslot = cs + cc * 4;
      int idx = (int)cim[ql * 8 + cslot];
      const float* mr = xb32 + (size_t)idx * C_;
      float a0 = 0.f, a1 = 0.f, a2 = 0.f, a3 = 0.f;
#pragma unroll 8
      for (int i = 0; i < 32; ++i) {
        f32x4 qv = *(const f32x4*)&qr[i * 4];
        float4 mv = *(const float4*)&mr[i * 4];
        a0 = fmaf(qv[0], mv.x, a0); a1 = fmaf(qv[1], mv.y, a1);
        a2 = fmaf(qv[2], mv.z, a2); a3 = fmaf(qv[3], mv.w, a3);
      }
      float dot = (a0 + a1) + (a2 + a3);
      sdv[ql * 8 + cslot] = xxb[idx] - 2.f * dot;
    }
  }
  __syncthreads();
  if (t < 64) {
    float dloc[8]; int iloc[8];
#pragma unroll
    for (int j = 0; j < 8; ++j) { dloc[j] = sdv[t * 8 + j]; iloc[j] = (int)cim[t * 8 + j]; }
    u32 used = 0;
#pragma unroll
    for (int s = 0; s < 4; ++s) {
      float bdv = 1e30f; int bidx = 0x7fffffff; int bj = 0;
#pragma unroll
      for (int j = 0; j < 8; ++j) {
        if (!((used >> j) & 1)) {
          bool bet = (dloc[j] < bdv) || (dloc[j] == bdv && iloc[j] < bidx);
          if (bet) { bdv = dloc[j]; bidx = iloc[j]; bj = j; }
        }
      }
      used |= 1u << bj;
      knn_out[((size_t)b * N_ + q0 + t) * K_ + s] = bidx;
    }
  }
}

// ============ agemm: ag[m][384] = wg @ [x; relu(x)] slices, biases folded ============
__global__ __launch_bounds__(256, 2) void agemm_kernel(
    const u16* __restrict__ xh, const u16* __restrict__ wg,
    const float* __restrict__ b1, const float* __restrict__ b2,
    u16* __restrict__ ag) {
  __shared__ __align__(16) char sm[66560];
  u16* outT = (u16*)(sm + 16384);
  const int b = blockIdx.y, m0 = blockIdx.x * 64;
  const int t = threadIdx.x, lane = t & 63, wv = t >> 6, lq = t & 15, lh = (t >> 4) & 3;
  const u16* xhb = xh + (size_t)b * N_ * C_;

  {
    const char* s = (const char*)(xhb + (size_t)m0 * C_);
#pragma unroll
    for (int c = 0; c < 4; ++c) {
      int off = (wv * 4 + c) * 1024;
      glds16(s + off + lane * 16, sm + off);
    }
  }

  s16x8 af[6][4];
#pragma unroll
  for (int rt = 0; rt < 6; ++rt)
#pragma unroll
    for (int ks = 0; ks < 4; ++ks)
      af[rt][ks] = *(const s16x8*)&wg[(size_t)(wv * 96 + rt * 16 + lq) * 128 + ks * 32 + lh * 8];

  f32x4 acc[6][4];
#pragma unroll
  for (int rt = 0; rt < 6; ++rt)
#pragma unroll
    for (int cg = 0; cg < 4; ++cg) acc[rt][cg] = (f32x4){0.f, 0.f, 0.f, 0.f};

  asm volatile("s_waitcnt vmcnt(0)");
  __syncthreads();

#pragma unroll
  for (int cg = 0; cg < 4; ++cg) {
    s16x8 braw[4], brel[4];
#pragma unroll
    for (int ks = 0; ks < 4; ++ks) {
      int row = cg * 16 + lq;
      braw[ks] = *(const s16x8*)(sm + row * 256 + (((ks * 4 + lh) ^ (lq & 7)) * 16));
      brel[ks] = relu8(braw[ks]);
    }
#pragma unroll
    for (int rt = 0; rt < 6; ++rt) {
      const bool rl = (wv * 96 + rt * 16) >= 128;
#pragma unroll
      for (int ks = 0; ks < 4; ++ks)
        acc[rt][cg] = __builtin_amdgcn_mfma_f32_16x16x32_bf16(
            af[rt][ks], rl ? brel[ks] : braw[ks], acc[rt][cg], 0, 0, 0);
    }
  }

#pragma unroll
  for (int rt = 0; rt < 6; ++rt) {
    const int ch0 = wv * 96 + rt * 16 + lh * 4;
    float bias[4];
#pragma unroll
    for (int r = 0; r < 4; ++r) {
      int c = ch0 + r;
      bias[r] = (c < 64) ? b1[c] : ((c >= 128 && c < 256) ? b2[c - 128] : 0.f);
    }
#pragma unroll
    for (int cg = 0; cg < 4; ++cg) {
      bf16x4 st;
#pragma unroll
      for (int r = 0; r < 4; ++r) st[r] = (__bf16)(acc[rt][cg][r] + bias[r]);
      *(bf16x4*)&outT[(size_t)(cg * 16 + lq) * 392 + ch0] = st;
    }
  }
  __syncthreads();

  {
    const int row = t >> 2, p = t & 3;
#pragma unroll
    for (int k = 0; k < 12; ++k) {
      int seg = k * 4 + p;
      *(u32x4*)&ag[((size_t)b * N_ + m0 + row) * AGC + seg * 8] =
          *(const u32x4*)&outT[(size_t)row * 392 + seg * 8];
    }
  }
}

// ============ fused_ag: gathers of precomputed ag + small GEMMs ============
__global__ __launch_bounds__(256, 3) void fused_ag(
    const u16* __restrict__ ag, const u16* __restrict__ wh,
    const int* __restrict__ knn_idx,
    const float* __restrict__ b3, float* __restrict__ out) {
  __shared__ __align__(16) char fsm[44032];
  u16* e1T = (u16*)fsm;
  u16* s2T = (u16*)(fsm + 9216);
  u16* e2T = (u16*)(fsm + 26624);
  float* oSt = (float*)fsm;   // [64][36], aliases e1T after p2 frag reads

  const int t = threadIdx.x, wv = t >> 6, lq = t & 15, lh = (t >> 4) & 3;
  const int b = blockIdx.y, n0 = blockIdx.x * 16;
  const u16* agb = ag + (size_t)b * N_ * AGC;
  const u16* w2h = wh + 16384;   // [128][320]
  const u16* w3h = wh + 57344;   // [64][64]

  s16x8 w2f[2][2];
#pragma unroll
  for (int rt = 0; rt < 2; ++rt)
#pragma unroll
    for (int ks = 0; ks < 2; ++ks)
      w2f[rt][ks] = *(const s16x8*)&w2h[(size_t)(wv * 32 + rt * 16 + lq) * ED_ + ks * 32 + lh * 8];
  const s16x8 w3a = *(const s16x8*)&w3h[(size_t)(wv * 16 + lq) * O_ + lh * 8];
  const s16x8 w3b = *(const s16x8*)&w3h[(size_t)(wv * 16 + lq) * O_ + 32 + lh * 8];
  const float4 b3v = *(const float4*)&b3[wv * 16 + lh * 4];

  {
    const int col = t >> 2, p = t & 3;
    const int n = n0 + (col >> 2);
    const int nid = knn_idx[((size_t)b * N_ + n) * K_ + (col & 3)];
    const u16* rc = agb + (size_t)n * AGC;
    const u16* rn = agb + (size_t)nid * AGC;
#pragma unroll
    for (int q = 0; q < 2; ++q) {
      s16x8 va = *(const s16x8*)&rc[p * 16 + q * 8];
      s16x8 vb = *(const s16x8*)&rn[64 + p * 16 + q * 8];
      bf16x8 r;
#pragma unroll
      for (int j = 0; j < 8; ++j)
        r[j] = (__bf16)fmaxf(bf2f((u16)va[j]) + bf2f((u16)vb[j]), 0.f);
      *(bf16x8*)&e1T[(size_t)col * 72 + p * 16 + q * 8] = r;
    }
#pragma unroll
    for (int q = 0; q < 4; ++q) {
      s16x8 va = *(const s16x8*)&rc[128 + p * 32 + q * 8];
      s16x8 vb = *(const s16x8*)&rn[256 + p * 32 + q * 8];
      bf16x8 r;
#pragma unroll
      for (int j = 0; j < 8; ++j)
        r[j] = (__bf16)(bf2f((u16)va[j]) + bf2f((u16)vb[j]));
      *(bf16x8*)&s2T[(size_t)col * 136 + p * 32 + q * 8] = r;
    }
  }
  __syncthreads();   // B1

  {
    f32x4 acc[2][4];
#pragma unroll
    for (int rt = 0; rt < 2; ++rt)
#pragma unroll
      for (int cg = 0; cg < 4; ++cg) acc[rt][cg] = (f32x4){0.f, 0.f, 0.f, 0.f};
#pragma unroll
    for (int ks = 0; ks < 2; ++ks)
#pragma unroll
      for (int cg = 0; cg < 4; ++cg) {
        s16x8 bf = *(const s16x8*)&e1T[(size_t)(cg * 16 + lq) * 72 + ks * 32 + lh * 8];
#pragma unroll
        for (int rt = 0; rt < 2; ++rt)
          acc[rt][cg] = __builtin_amdgcn_mfma_f32_16x16x32_bf16(w2f[rt][ks], bf, acc[rt][cg], 0, 0, 0);
      }
#pragma unroll
    for (int rt = 0; rt < 2; ++rt)
#pragma unroll
      for (int cg = 0; cg < 4; ++cg) {
        const int col = cg * 16 + lq;
        const int j0 = wv * 32 + rt * 16 + lh * 4;
        ushort4 sv = *(const ushort4*)&s2T[(size_t)col * 136 + j0];
        bf16x4 st;
        st[0] = (__bf16)fmaxf(acc[rt][cg][0] + bf2f(sv.x), 0.f);
        st[1] = (__bf16)fmaxf(acc[rt][cg][1] + bf2f(sv.y), 0.f);
        st[2] = (__bf16)fmaxf(acc[rt][cg][2] + bf2f(sv.z), 0.f);
        st[3] = (__bf16)fmaxf(acc[rt][cg][3] + bf2f(sv.w), 0.f);
        *(bf16x4*)&e2T[(size_t)col * 136 + j0] = st;
      }
  }
  __syncthreads();   // B2

  {
#pragma unroll
    for (int cg = 0; cg < 8; ++cg) {
      int col = cg * 16 + lq;
      int nl = col >> 3, rr = (col >> 2) & 1, kk = col & 3;
      int row = nl * 4 + kk;
      s16x8 f1 = *(const s16x8*)&e2T[(size_t)row * 136 + rr * 64 + lh * 8];
      s16x8 f2 = *(const s16x8*)&e2T[(size_t)row * 136 + rr * 64 + 32 + lh * 8];
      f32x4 acc = {0.f, 0.f, 0.f, 0.f};
      acc = __builtin_amdgcn_mfma_f32_16x16x32_bf16(w3a, f1, acc, 0, 0, 0);
      acc = __builtin_amdgcn_mfma_f32_16x16x32_bf16(w3b, f2, acc, 0, 0, 0);
      float vv[4];
#pragma unroll
      for (int r = 0; r < 4; ++r) {
        float v = acc[r];
        v = fmaxf(v, __shfl_xor(v, 1));
        v = fmaxf(v, __shfl_xor(v, 2));
        vv[r] = v;
      }
      if ((lq & 3) == 0) {
        int mloc = col >> 2;
        int o = wv * 16 + lh * 4;
        const float b3a[4] = {b3v.x, b3v.y, b3v.z, b3v.w};
#pragma unroll
        for (int r = 0; r < 4; ++r) oSt[(size_t)(o + r) * 36 + mloc] = vv[r] + b3a[r];
      }
    }
  }
  __syncthreads();   // B3

#pragma unroll
  for (int io = 0; io < 2; ++io) {
    int u = t + io * 256;
    int o = u >> 3, seg = u & 7;
    *(float4*)&out[((size_t)b * O_ + o) * NM_ + n0 * 2 + seg * 4] =
        *(const float4*)&oSt[(size_t)o * 36 + seg * 4];
  }
}

// ============ slow fallback kernels ============
__global__ __launch_bounds__(256) void xx_kernel(const float* __restrict__ x,
                                                 float* __restrict__ xx) {
  int g = blockIdx.x * 256 + threadIdx.x;
  int b = g >> 11;
  int n = g & (N_ - 1);
  const float* xp = x + (size_t)b * C_ * N_ + n;
  float s = 0.f;
#pragma unroll 8
  for (int c = 0; c < C_; ++c) { float v = xp[(size_t)c * N_]; s += v * v; }
  xx[g] = s;
}

__global__ __launch_bounds__(256) void knn_kernel(const float* __restrict__ x,
                                                  const float* __restrict__ xx,
                                                  int* __restrict__ knn_out) {
  __shared__ __align__(16) float qT[C_ * 64];
  __shared__ __align__(16) float mT[C_ * 64];
  const int b = blockIdx.y;
  const int q0 = blockIdx.x * 64;
  const int t = threadIdx.x;
  const float* xb = x + (size_t)b * C_ * N_;
  const float* xxb = xx + b * N_;
  for (int i = t; i < C_ * 64; i += 256) {
    int c = i >> 6, q = i & 63;
    qT[i] = xb[(size_t)c * N_ + q0 + q];
  }
  const int tq = t & 15;
  const int tm = t >> 4;
  float bd[4][4]; int bi[4][4];
#pragma unroll
  for (int a = 0; a < 4; ++a)
#pragma unroll
    for (int s = 0; s < 4; ++s) { bd[a][s] = 1e30f; bi[a][s] = 0; }
  for (int m0 = 0; m0 < N_; m0 += 64) {
    __syncthreads();
    for (int i = t; i < C_ * 64; i += 256) {
      int c = i >> 6, m = i & 63;
      mT[i] = xb[(size_t)c * N_ + m0 + m];
    }
    __syncthreads();
    float acc[4][4];
#pragma unroll
    for (int a = 0; a < 4; ++a)
#pragma unroll
      for (int j = 0; j < 4; ++j) acc[a][j] = 0.f;
#pragma unroll 4
    for (int c = 0; c < C_; ++c) {
      float4 qv = *(const float4*)&qT[c * 64 + tq * 4];
      float4 mv = *(const float4*)&mT[c * 64 + tm * 4];
      float qa[4] = {qv.x, qv.y, qv.z, qv.w};
      float ma[4] = {mv.x, mv.y, mv.z, mv.w};
#pragma unroll
      for (int a = 0; a < 4; ++a)
#pragma unroll
        for (int j = 0; j < 4; ++j) acc[a][j] += qa[a] * ma[j];
    }
#pragma unroll
    for (int j = 0; j < 4; ++j) {
      float xm = xxb[m0 + tm * 4 + j];
      int id = m0 + tm * 4 + j;
#pragma unroll
      for (int a = 0; a < 4; ++a) {
        float d = xm - 2.f * acc[a][j];
        if (d < bd[a][3]) {
          bd[a][3] = d; bi[a][3] = id;
#pragma unroll
          for (int s = 3; s > 0; --s)
            if (bd[a][s] < bd[a][s - 1]) {
              float td = bd[a][s]; bd[a][s] = bd[a][s - 1]; bd[a][s - 1] = td;
              int ti = bi[a][s]; bi[a][s] = bi[a][s - 1]; bi[a][s - 1] = ti;
            }
        }
      }
    }
  }
  __syncthreads();
  float* cd = qT;
  int* ci = (int*)mT;
#pragma unroll
  for (int a = 0; a < 4; ++a) {
    int q = tq * 4 + a;
#pragma unroll
    for (int s = 0; s < 4; ++s) {
      cd[q * 64 + tm * 4 + s] = bd[a][s];
      ci[q * 64 + tm * 4 + s] = bi[a][s];
    }
  }
  __syncthreads();
  if (t < 64) {
    float fd[4]; int fi[4];
#pragma unroll
    for (int s = 0; s < 4; ++s) { fd[s] = 1e30f; fi[s] = 0; }
    for (int j = 0; j < 64; ++j) {
      float d = cd[t * 64 + j];
      int id = ci[t * 64 + j];
      if (d < fd[3]) {
        fd[3] = d; fi[3] = id;
#pragma unroll
        for (int s = 3; s > 0; --s)
          if (fd[s] < fd[s - 1]) {
            float td = fd[s]; fd[s] = fd[s - 1]; fd[s - 1] = td;
            int ti = fi[s]; fi[s] = fi[s - 1]; fi[s - 1] = ti;
          }
      }
    }
#pragma unroll
    for (int s = 0; s < 4; ++s)
      knn_out[(b * N_ + q0 + t) * K_ + s] = fi[s];
  }
}

__global__ __launch_bounds__(256, 5) void fused_fb(
    const float* __restrict__ x, const int* __restrict__ knn_idx,
    const float* __restrict__ w1, const float* __restrict__ b1,
    const float* __restrict__ w2, const float* __restrict__ b2,
    const float* __restrict__ w3, const float* __restrict__ b3,
    float* __restrict__ out) {
  __shared__ __align__(16) char fsm[30976];
  __bf16 (*cT)[136]  = (__bf16(*)[136])(fsm);
  __bf16 (*e1T)[72]  = (__bf16(*)[72])(fsm + 4352);
  float  (*oSt)[36]  = (float(*)[36])(fsm + 4352);
  __bf16 (*nT)[136]  = (__bf16(*)[136])(fsm + 13568);
  __bf16 (*e2T)[136] = (__bf16(*)[136])(fsm + 13568);

  const int b  = blockIdx.y;
  const int n0 = blockIdx.x * 16;
  const int t  = threadIdx.x;
  const float* xb = x + (size_t)b * C_ * N_;

  {
    const int stn = t >> 4, stc = t & 15;
    const int kbase = (b * N_ + n0) * K_;
    const float* srcc = xb + (size_t)(stc * 8) * N_ + n0 + stn;
    bf16x8 raw;
#pragma unroll
    for (int j = 0; j < 8; ++j) raw[j] = (__bf16)srcc[(size_t)j * N_];
    *(bf16x8*)&cT[stn][stc * 8] = raw;
#pragma unroll
    for (int it = 0; it < 4; ++it) {
      int col = stn + 16 * it;
      int nid = knn_idx[kbase + col];
      const float* src = xb + (size_t)(stc * 8) * N_ + nid;
      bf16x8 rw;
#pragma unroll
      for (int j = 0; j < 8; ++j) rw[j] = (__bf16)src[(size_t)j * N_];
      *(bf16x8*)&nT[col][stc * 8] = rw;
    }
  }
  __syncthreads();

  const int lq = t & 15;
  const int lh = (t >> 4) & 3;
  const int wv = t >> 6;

  {
    const float* w1r = w1 + (size_t)(wv * 16 + lq) * C2_;
    f32x4 acc[4];
#pragma unroll
    for (int cg = 0; cg < 4; ++cg) acc[cg] = (f32x4){0.f, 0.f, 0.f, 0.f};
#pragma unroll
    for (int ks = 0; ks < 8; ++ks) {
      s16x8 a = ldw_bf16(w1r + ks * 32 + lh * 8);
#pragma unroll
      for (int cg = 0; cg < 4; ++cg) {
        const __bf16* bp = (ks < 4)
            ? &cT[cg * 4 + (lq >> 2)][ks * 32 + lh * 8]
            : &nT[cg * 16 + lq][(ks - 4) * 32 + lh * 8];
        acc[cg] = __builtin_amdgcn_mfma_f32_16x16x32_bf16(
            a, *(const s16x8*)bp, acc[cg], 0, 0, 0);
      }
    }
#pragma unroll
    for (int cg = 0; cg < 4; ++cg) {
      bf16x4 st;
#pragma unroll
      for (int r = 0; r < 4; ++r) {
        float v = acc[cg][r] + b1[wv * 16 + lh * 4 + r];
        st[r] = (__bf16)fmaxf(v, 0.f);
      }
      *(bf16x4*)&e1T[cg * 16 + lq][wv * 16 + lh * 4] = st;
    }
  }
  __syncthreads();

  f32x4 acc2[2][4];
  {
    const float* w2r0 = w2 + (size_t)(wv * 32 + lq) * ED_;
    const float* w2r1 = w2r0 + (size_t)16 * ED_;
#pragma unroll
    for (int ro = 0; ro < 2; ++ro)
#pragma unroll
      for (int cg = 0; cg < 4; ++cg) acc2[ro][cg] = (f32x4){0.f, 0.f, 0.f, 0.f};
#pragma unroll
    for (int ks = 0; ks < 10; ++ks) {
      s16x8 a0 = ldw_bf16(w2r0 + ks * 32 + lh * 8);
      s16x8 a1 = ldw_bf16(w2r1 + ks * 32 + lh * 8);
#pragma unroll
      for (int cg = 0; cg < 4; ++cg) {
        s16x8 bf;
        if (ks < 2)      bf = *(const s16x8*)&e1T[cg * 16 + lq][ks * 32 + lh * 8];
        else if (ks < 6) bf = relu8(*(const s16x8*)&cT[cg * 4 + (lq >> 2)][(ks - 2) * 32 + lh * 8]);
        else             bf = relu8(*(const s16x8*)&nT[cg * 16 + lq][(ks - 6) * 32 + lh * 8]);
        acc2[0][cg] = __builtin_amdgcn_mfma_f32_16x16x32_bf16(a0, bf, acc2[0][cg], 0, 0, 0);
        acc2[1][cg] = __builtin_amdgcn_mfma_f32_16x16x32_bf16(a1, bf, acc2[1][cg], 0, 0, 0);
      }
    }
  }
  __syncthreads();
  {
#pragma unroll
    for (int ro = 0; ro < 2; ++ro)
#pragma unroll
      for (int cg = 0; cg < 4; ++cg) {
        bf16x4 st;
#pragma unroll
        for (int r = 0; r < 4; ++r) {
          float v = acc2[ro][cg][r] + b2[wv * 32 + ro * 16 + lh * 4 + r];
          st[r] = (__bf16)fmaxf(v, 0.f);
        }
        *(bf16x4*)&e2T[cg * 16 + lq][wv * 32 + ro * 16 + lh * 4] = st;
      }
  }
  __syncthreads();

  {
    const float* w3r = w3 + (size_t)(wv * 16 + lq) * O_;
    s16x8 a0 = ldw_bf16(w3r + lh * 8);
    s16x8 a1 = ldw_bf16(w3r + 32 + lh * 8);
#pragma unroll
    for (int cg = 0; cg < 8; ++cg) {
      int col = cg * 16 + lq;
      int nl = col >> 3, rr = (col >> 2) & 1, kk = col & 3;
      const __bf16* base = &e2T[nl * 4 + kk][rr * 64];
      f32x4 acc = {0.f, 0.f, 0.f, 0.f};
      acc = __builtin_amdgcn_mfma_f32_16x16x32_bf16(a0, *(const s16x8*)(base + lh * 8),      acc, 0, 0, 0);
      acc = __builtin_amdgcn_mfma_f32_16x16x32_bf16(a1, *(const s16x8*)(base + 32 + lh * 8), acc, 0, 0, 0);
      float vv[4];
#pragma unroll
      for (int r = 0; r < 4; ++r) {
        float v = acc[r];
        v = fmaxf(v, __shfl_xor(v, 1));
        v = fmaxf(v, __shfl_xor(v, 2));
        vv[r] = v;
      }
      if ((lq & 3) == 0) {
        int mloc = col >> 2;
        int o = wv * 16 + lh * 4;
#pragma unroll
        for (int r = 0; r < 4; ++r) oSt[o + r][mloc] = vv[r] + b3[o + r];
      }
    }
  }
  __syncthreads();

#pragma unroll
  for (int it = 0; it < 2; ++it) {
    int u = t + it * 256;
    int o = u >> 3, seg = u & 7;
    *(float4*)&out[((size_t)b * O_ + o) * NM_ + n0 * 2 + seg * 4] =
        *(const float4*)&oSt[o][seg * 4];
  }
}

extern "C" void kernel_launch(void* const* d_in, const int* in_sizes, int n_in,
                              void* d_out, int out_size, void* d_ws, size_t ws_size,
                              hipStream_t stream) {
  const float* x  = (const float*)d_in[0];
  const float* w1 = (const float*)d_in[1];
  const float* b1 = (const float*)d_in[2];
  const float* w2 = (const float*)d_in[3];
  const float* b2 = (const float*)d_in[4];
  const float* w3 = (const float*)d_in[5];
  const float* b3 = (const float*)d_in[6];
  float* out = (float*)d_out;

  // ---- layout: [ag 24MB (xT32 @0 inside) | xh | xx | knn | wh | wg]
  // xT32 aliases ag[0..16MB): consumed by knn_mfma's fused rerank before agemm writes ag.
  const size_t AGB      = (size_t)B_ * N_ * AGC * 2;          // 25,165,824
  const size_t off_xhN  = AGB;
  const size_t off_xxN  = off_xhN + (size_t)B_ * N_ * C_ * 2;
  const size_t off_knnN = off_xxN + (size_t)B_ * N_ * 4;
  const size_t off_whN  = off_knnN + (size_t)B_ * N_ * K_ * 4;
  const size_t off_wgN  = off_whN + (size_t)61440 * 2;
  const size_t NEED_NEW = off_wgN + (size_t)AGC * 128 * 2;

  if (ws_size >= NEED_NEW) {
    u16*   agp  = (u16*)d_ws;
    float* xT32 = (float*)d_ws;                         // aliases ag[0..16MB)
    u16*   xhp  = (u16*)((char*)d_ws + off_xhN);
    float* xx   = (float*)((char*)d_ws + off_xxN);
    int*   knn  = (int*)((char*)d_ws + off_knnN);
    u16*   whp  = (u16*)((char*)d_ws + off_whN);
    u16*   wgp  = (u16*)((char*)d_ws + off_wgN);

    hipLaunchKernelGGL(prep_kernel, dim3(N_ / 64, B_ + 1), dim3(256), 0, stream,
                       x, w1, w2, w3, xT32, xhp, xx, whp, wgp);
    hipLaunchKernelGGL(knn_mfma, dim3(N_ / 64, B_), dim3(256), 0, stream,
                       xhp, xT32, xx, knn);
    hipLaunchKernelGGL(agemm_kernel, dim3(N_ / 64, B_), dim3(256), 0, stream,
                       xhp, wgp, b1, b2, agp);
    hipLaunchKernelGGL(fused_ag, dim3(N_ / 16, B_), dim3(256), 0, stream,
                       agp, whp, knn, b3, out);
  } else {
    float* xx = (float*)d_ws;
    int* knn = (int*)((char*)d_ws + (size_t)B_ * N_ * 4);
    hipLaunchKernelGGL(xx_kernel, dim3((B_ * N_) / 256), dim3(256), 0, stream, x, xx);
    hipLaunchKernelGGL(knn_kernel, dim3(N_ / 64, B_), dim3(256), 0, stream, x, xx, knn);
    hipLaunchKernelGGL(fused_fb, dim3(N_ / 16, B_), dim3(256), 0, stream,
                       x, knn, w1, b1, w2, b2, w3, b3, out);
  }
}